// Round 10
// baseline (388.670 us; speedup 1.0000x reference)
//
#include <hip/hip_runtime.h>

// Problem: B=1, L=4096, EMBED=1024, 16 heads x 64
static constexpr int L_SEQ = 4096;
static constexpr int EMBED = 1024;
static constexpr int HEADS = 16;
static constexpr int HD    = 64;

typedef unsigned short ushortT;
typedef __attribute__((ext_vector_type(8)))  short short8;   // 8 x bf16 (4 VGPR)
typedef __attribute__((ext_vector_type(4)))  float f32x4;

#define LOG2E 1.4426950408889634f

__device__ __forceinline__ ushortT f2bf(float f) {
  unsigned u = __builtin_bit_cast(unsigned, f);
  u += 0x7fffu + ((u >> 16) & 1u);          // round-to-nearest-even
  return (ushortT)(u >> 16);
}
__device__ __forceinline__ float bf2f(ushortT s) {
  return __builtin_bit_cast(float, ((unsigned)s) << 16);
}

// ---- DPP 16-lane butterfly reduction (VALU pipe, replaces ds_swizzle shfl) ----
// ctrls: 0xB1 quad_perm xor1, 0x4E quad_perm xor2, 0x141 row_half_mirror
// (lane^7), 0x140 row_mirror (lane^15). After xor1+xor2 the partials are
// quad-uniform, so ^7 / ^15 deliver the same partner values as ^4 / ^8 ->
// bitwise-identical to the __shfl_xor(1,2,4,8) version.
// dpp_ctrl must be an integer-constant expression -> template parameter.
template <int CTRL>
__device__ __forceinline__ float fmax_dpp(float x) {
  int v = __builtin_amdgcn_mov_dpp(__builtin_bit_cast(int, x), CTRL, 0xF, 0xF, true);
  return fmaxf(x, __builtin_bit_cast(float, v));
}
template <int CTRL>
__device__ __forceinline__ float fadd_dpp(float x) {
  int v = __builtin_amdgcn_mov_dpp(__builtin_bit_cast(int, x), CTRL, 0xF, 0xF, true);
  return x + __builtin_bit_cast(float, v);
}
__device__ __forceinline__ float red16_max(float x) {
  x = fmax_dpp<0xB1>(x); x = fmax_dpp<0x4E>(x);
  x = fmax_dpp<0x141>(x); x = fmax_dpp<0x140>(x);
  return x;
}
__device__ __forceinline__ float red16_sum(float x) {
  x = fadd_dpp<0xB1>(x); x = fadd_dpp<0x4E>(x);
  x = fadd_dpp<0x141>(x); x = fadd_dpp<0x140>(x);
  return x;
}

// async global->LDS, 16B/lane; LDS dest is wave-uniform base + lane*16.
#define GLOAD_LDS16(g, l) \
  __builtin_amdgcn_global_load_lds((const __attribute__((address_space(1))) void*)(g), \
                                   (__attribute__((address_space(3))) void*)(l), 16, 0, 0)

// ---------------- fp32 -> bf16 cast, 8 elems/thread ----------------
__global__ void cast_bf16_k(const float* __restrict__ in, ushortT* __restrict__ out, int n8) {
  int i = blockIdx.x * blockDim.x + threadIdx.x;
  if (i >= n8) return;
  const float4* p = (const float4*)in;
  float4 a = p[2 * i], b = p[2 * i + 1];
  uint4 o;
  o.x = (unsigned)f2bf(a.x) | ((unsigned)f2bf(a.y) << 16);
  o.y = (unsigned)f2bf(a.z) | ((unsigned)f2bf(a.w) << 16);
  o.z = (unsigned)f2bf(b.x) | ((unsigned)f2bf(b.y) << 16);
  o.w = (unsigned)f2bf(b.z) | ((unsigned)f2bf(b.w) << 16);
  ((uint4*)out)[i] = o;
}

// fused 4-weight cast (each weight 1M elements), dsts contiguous at out
__global__ void cast4_bf16_k(const float* __restrict__ a, const float* __restrict__ b,
                             const float* __restrict__ c, const float* __restrict__ d,
                             ushortT* __restrict__ out) {
  int idx = blockIdx.x * blockDim.x + threadIdx.x;   // 4 * 131072
  int w = idx >> 17, i = idx & 131071;
  const float* src = (w == 0) ? a : (w == 1) ? b : (w == 2) ? c : d;
  const float4* p = (const float4*)src;
  float4 x = p[2 * i], y = p[2 * i + 1];
  uint4 o;
  o.x = (unsigned)f2bf(x.x) | ((unsigned)f2bf(x.y) << 16);
  o.y = (unsigned)f2bf(x.z) | ((unsigned)f2bf(x.w) << 16);
  o.z = (unsigned)f2bf(y.x) | ((unsigned)f2bf(y.y) << 16);
  o.w = (unsigned)f2bf(y.z) | ((unsigned)f2bf(y.w) << 16);
  ((uint4*)(out + ((size_t)w << 20)))[i] = o;
}

// ---------------- log2(size) ----------------
__global__ void l2size_k(const float* __restrict__ sz, float* __restrict__ l2s, int n) {
  int i = blockIdx.x * blockDim.x + threadIdx.x;
  if (i < n) l2s[i] = __log2f(sz[i]);
}

// ---------------- GEMM: C[M,N] = A[M,K] @ B[N,K]^T + bias ----------------
struct GemmArgs { const ushortT* B; const float* bias; void* dst; int mode; };
// mode 0: Q -> bf16 [h][t][64] * 0.125   mode 1: K -> bf16 [h][t][64]
// mode 2: V -> bf16 [h][64][t] (transposed)      mode 3: fp32 [m][1024]

__global__ __launch_bounds__(256, 3) void gemm_bt_k(
    const ushortT* __restrict__ A, GemmArgs g0, GemmArgs g1, GemmArgs g2)
{
  constexpr int K = 1024;
  __shared__ __align__(16) ushortT As[128 * 64];
  __shared__ __align__(16) ushortT Bs[128 * 64];

  GemmArgs g = (blockIdx.y == 0) ? g0 : ((blockIdx.y == 1) ? g1 : g2);
  const ushortT* __restrict__ Bw = g.B;

  const int tid = threadIdx.x;
  const int wv = tid >> 6, ln = tid & 63;
  const int mb = blockIdx.x & 31, nb = blockIdx.x >> 5;     // 32 x 8 blocks
  const int m0 = mb * 128, n0 = nb * 128;
  const int wr = wv >> 1, wc = wv & 1;
  const int lrow = ln & 15, lq = ln >> 4;

  const int rstg = wv * 8 + (ln >> 3);
  const int ustg = (ln & 7) ^ (ln >> 3);

  f32x4 acc[4][4] = {};

  for (int kt = 0; kt < K; kt += 64) {
#pragma unroll
    for (int i = 0; i < 4; ++i) {
      int r = i * 32 + rstg;
      GLOAD_LDS16(A  + (size_t)(m0 + r) * K + kt + (ustg << 3), As + i * 2048 + wv * 512);
      GLOAD_LDS16(Bw + (size_t)(n0 + r) * K + kt + (ustg << 3), Bs + i * 2048 + wv * 512);
    }
    __syncthreads();
#pragma unroll
    for (int ks = 0; ks < 2; ++ks) {
      short8 a[4], b[4];
#pragma unroll
      for (int mi = 0; mi < 4; ++mi) {
        int ra = wr * 64 + mi * 16 + lrow;
        int u = (ks * 4 + lq) ^ (ra & 7);
        a[mi] = *(const short8*)(As + ra * 64 + (u << 3));
      }
#pragma unroll
      for (int ni = 0; ni < 4; ++ni) {
        int rb = wc * 64 + ni * 16 + lrow;
        int u = (ks * 4 + lq) ^ (rb & 7);
        b[ni] = *(const short8*)(Bs + rb * 64 + (u << 3));
      }
#pragma unroll
      for (int mi = 0; mi < 4; ++mi)
#pragma unroll
        for (int ni = 0; ni < 4; ++ni)
          acc[mi][ni] = __builtin_amdgcn_mfma_f32_16x16x32_bf16(a[mi], b[ni], acc[mi][ni], 0, 0, 0);
    }
    __syncthreads();
  }

  const int mode = g.mode;
  if (mode <= 1) {
    ushortT* dst = (ushortT*)g.dst;
    const float sc = (mode == 0) ? 0.125f : 1.0f;
#pragma unroll
    for (int ni = 0; ni < 4; ++ni) {
      int n = n0 + wc * 64 + ni * 16 + lrow;
      float bsv = g.bias[n];
      size_t base = ((size_t)(n >> 6) * L_SEQ) * HD + (n & 63);
#pragma unroll
      for (int mi = 0; mi < 4; ++mi)
#pragma unroll
        for (int r = 0; r < 4; ++r) {
          int m = m0 + wr * 64 + mi * 16 + lq * 4 + r;
          dst[base + (size_t)m * HD] = f2bf((acc[mi][ni][r] + bsv) * sc);
        }
    }
  } else if (mode == 2) {
    ushortT* dst = (ushortT*)g.dst;
#pragma unroll
    for (int ni = 0; ni < 4; ++ni) {
      int n = n0 + wc * 64 + ni * 16 + lrow;     // n == h*64+hd
      float bsv = g.bias[n];
      size_t base = (size_t)n * L_SEQ;
#pragma unroll
      for (int mi = 0; mi < 4; ++mi)
#pragma unroll
        for (int r = 0; r < 4; ++r) {
          int m = m0 + wr * 64 + mi * 16 + lq * 4 + r;
          dst[base + m] = f2bf(acc[mi][ni][r] + bsv);
        }
    }
  } else {
    float* dst = (float*)g.dst;
#pragma unroll
    for (int ni = 0; ni < 4; ++ni) {
      int n = n0 + wc * 64 + ni * 16 + lrow;
      float bsv = g.bias[n];
#pragma unroll
      for (int mi = 0; mi < 4; ++mi)
#pragma unroll
        for (int r = 0; r < 4; ++r) {
          int m = m0 + wr * 64 + mi * 16 + lq * 4 + r;
          dst[(size_t)m * EMBED + n] = acc[mi][ni][r] + bsv;
        }
    }
  }
}

// ---------------- flash attention (16x16 structure + T14 reg-prefetch) --------
// 1024 blocks, XCD head-clustering swizzle (FETCH 70->12MB). Softmax via DPP
// butterfly on the VALU pipe (R9, -25%). NEW (T14): K/V tile t+1 is prefetched
// into 16 VGPRs via plain global_load_dwordx4 at the top of tile t, then
// ds_write_b128'd into the SAME single LDS buffer between two barriers after
// compute — HBM/L2 latency hides under the whole compute phase, LDS stays
// 25600B (no R6 occupancy cliff). Values bitwise-identical.
__global__ __launch_bounds__(256, 4) void attn_k(
    const ushortT* __restrict__ Q,   // [16][4096][64], pre-scaled by 0.125
    const ushortT* __restrict__ Kb,  // [16][4096][64]
    const ushortT* __restrict__ Vt,  // [16][64][4096]
    const float*   __restrict__ l2s, // [4096] log2(size)
    ushortT* __restrict__ O)         // [4096][1024] bf16
{
  __shared__ __align__(16) ushortT Ks[64 * 64];
  __shared__ __align__(16) ushortT Vs[64 * 64];
  __shared__ __align__(16) ushortT Ps[4][16 * 72];  // per-wave, +8 pad

  const int id = blockIdx.x;                 // 0..1023
  const int xcd = id & 7, s = id >> 3;
  const int h  = xcd * 2 + (s >> 6);         // head (2 per XCD)
  const int q0 = (s & 63) * 64;              // q-tile base

  const int tid = threadIdx.x;
  const int wv = tid >> 6, ln = tid & 63;
  const int lrow = ln & 15, lq = ln >> 4;

  short8 qf0, qf1;  // hoisted Q A-fragments (row = lane&15, k contiguous)
  {
    const ushortT* qp = Q + ((size_t)h * L_SEQ + q0 + wv * 16 + lrow) * HD + lq * 8;
    qf0 = *(const short8*)qp;
    qf1 = *(const short8*)(qp + 32);
  }

  f32x4 o[4] = {};
  float mrun[4], lrun[4];
#pragma unroll
  for (int r = 0; r < 4; ++r) { mrun[r] = -1e30f; lrun[r] = 0.f; }

  const int rstg = wv * 8 + (ln >> 3);
  const int ustg = (ln & 7) ^ (ln >> 3);

  // per-thread staging base pointers (row rstg, pre-swizzled slot ustg)
  const ushortT* kbase = Kb + ((size_t)h * L_SEQ + rstg) * HD + (ustg << 3);
  const ushortT* vbase = Vt + ((size_t)(h * HD) + rstg) * L_SEQ + (ustg << 3);

  // prologue: stage tile 0 via global_load_lds
#pragma unroll
  for (int i = 0; i < 2; ++i) {
    GLOAD_LDS16(kbase + (size_t)(i * 32) * HD,    Ks + i * 2048 + wv * 512);
    GLOAD_LDS16(vbase + (size_t)(i * 32) * L_SEQ, Vs + i * 2048 + wv * 512);
  }
  __syncthreads();

  constexpr int NT = L_SEQ / 64;
  for (int t = 0; t < NT; ++t) {
    const int t0 = t * 64;
    const bool have = (t + 1 < NT);

    // T14: issue prefetch of tile t+1 into registers (no wait)
    uint4 kp[2], vp[2];
    if (have) {
      const int t1 = t0 + 64;
#pragma unroll
      for (int i = 0; i < 2; ++i) {
        kp[i] = *(const uint4*)(kbase + ((size_t)(t1 + i * 32)) * HD);
        vp[i] = *(const uint4*)(vbase + (size_t)(i * 32) * L_SEQ + t1);
      }
    }

    // S = Q K^T  (rows q, cols key)
    f32x4 sfr[4] = {};
    __builtin_amdgcn_s_setprio(1);
#pragma unroll
    for (int ks = 0; ks < 2; ++ks) {
      short8 qa = ks ? qf1 : qf0;
#pragma unroll
      for (int f = 0; f < 4; ++f) {
        int key = f * 16 + lrow;
        int u = (ks * 4 + lq) ^ (key & 7);
        short8 kb = *(const short8*)(Ks + key * 64 + (u << 3));
        sfr[f] = __builtin_amdgcn_mfma_f32_16x16x32_bf16(qa, kb, sfr[f], 0, 0, 0);
      }
    }
    __builtin_amdgcn_s_setprio(0);

    // base-2 logits + log2(size_key)
#pragma unroll
    for (int f = 0; f < 4; ++f) {
      float bias = l2s[t0 + f * 16 + lrow];
#pragma unroll
      for (int r = 0; r < 4; ++r)
        sfr[f][r] = sfr[f][r] * LOG2E + bias;
    }

    // online softmax; row r lives in 16-lane group (lanes share lq)
    float alpha[4];
    bool noop = true;
#pragma unroll
    for (int r = 0; r < 4; ++r) {
      float t1 = fmaxf(fmaxf(sfr[0][r], sfr[1][r]), fmaxf(sfr[2][r], sfr[3][r]));
      t1 = red16_max(t1);                        // DPP butterfly (VALU pipe)
      float mnew = fmaxf(mrun[r], t1);
      alpha[r] = __builtin_amdgcn_exp2f(mrun[r] - mnew);
      mrun[r] = mnew;
      float rs = 0.f;
#pragma unroll
      for (int f = 0; f < 4; ++f) {
        float pv = __builtin_amdgcn_exp2f(sfr[f][r] - mnew);
        sfr[f][r] = pv;
        rs += pv;
      }
      rs = red16_sum(rs);                        // DPP butterfly (VALU pipe)
      lrun[r] = lrun[r] * alpha[r] + rs;
      noop = noop && (alpha[r] == 1.0f);
    }
    if (!__all(noop)) {              // skip O-rescale when all alphas == 1
#pragma unroll
      for (int df = 0; df < 4; ++df)
#pragma unroll
        for (int r = 0; r < 4; ++r) o[df][r] *= alpha[r];
    }

    // P -> per-wave LDS (C layout in, A layout out), padded to 72 shorts/row
    ushortT* pb = &Ps[wv][0];
#pragma unroll
    for (int f = 0; f < 4; ++f)
#pragma unroll
      for (int r = 0; r < 4; ++r)
        pb[(lq * 4 + r) * 72 + f * 16 + lrow] = f2bf(sfr[f][r]);

    asm volatile("s_waitcnt lgkmcnt(0)" ::: "memory");  // cross-lane LDS dep
    __builtin_amdgcn_sched_barrier(0);

    short8 pa0 = *(const short8*)(pb + lrow * 72 + lq * 8);
    short8 pa1 = *(const short8*)(pb + lrow * 72 + 32 + lq * 8);

    // O += P @ V   (B operand from transposed-V tile: row=d, k=key)
    __builtin_amdgcn_s_setprio(1);
#pragma unroll
    for (int ks = 0; ks < 2; ++ks) {
      short8 pa = ks ? pa1 : pa0;
#pragma unroll
      for (int df = 0; df < 4; ++df) {
        int d = df * 16 + lrow;
        int u = (ks * 4 + lq) ^ (d & 7);
        short8 vb = *(const short8*)(Vs + d * 64 + (u << 3));
        o[df] = __builtin_amdgcn_mfma_f32_16x16x32_bf16(pa, vb, o[df], 0, 0, 0);
      }
    }
    __builtin_amdgcn_s_setprio(0);

    // T14: land the prefetched tile into LDS (compiler inserts vmcnt wait)
    if (have) {
      __syncthreads();               // all waves done reading tile t
#pragma unroll
      for (int i = 0; i < 2; ++i) {
        *(uint4*)(Ks + i * 2048 + wv * 512 + ln * 8) = kp[i];
        *(uint4*)(Vs + i * 2048 + wv * 512 + ln * 8) = vp[i];
      }
      __syncthreads();               // tile t+1 visible
    }
  }

  // epilogue: divide by softmax denom, store bf16 [t][h*64+d]
#pragma unroll
  for (int df = 0; df < 4; ++df)
#pragma unroll
    for (int r = 0; r < 4; ++r) {
      int q = q0 + wv * 16 + lq * 4 + r;
      O[(size_t)q * EMBED + h * HD + df * 16 + lrow] = f2bf(o[df][r] / lrun[r]);
    }
}

// ---------------- metric = mean over heads of K ----------------
__global__ void metric_k(const ushortT* __restrict__ Kb, float* __restrict__ out) {
  int idx = blockIdx.x * blockDim.x + threadIdx.x;   // t*8 + c8
  int t = idx >> 3, c8 = idx & 7;
  float acc[8] = {};
#pragma unroll
  for (int h = 0; h < HEADS; ++h) {
    short8 v = *(const short8*)(Kb + ((size_t)h * L_SEQ + t) * HD + c8 * 8);
#pragma unroll
    for (int j = 0; j < 8; ++j) acc[j] += bf2f((ushortT)v[j]);
  }
  float* dst = out + (size_t)t * HD + c8 * 8;
#pragma unroll
  for (int j = 0; j < 8; ++j) dst[j] = acc[j] * (1.0f / 16.0f);
}

extern "C" void kernel_launch(void* const* d_in, const int* in_sizes, int n_in,
                              void* d_out, int out_size, void* d_ws, size_t ws_size,
                              hipStream_t stream) {
  const float* hs = (const float*)d_in[0];
  const float* sz = (const float*)d_in[1];
  const float* wq = (const float*)d_in[2];
  const float* bq = (const float*)d_in[3];
  const float* wk = (const float*)d_in[4];
  const float* bk = (const float*)d_in[5];
  const float* wv = (const float*)d_in[6];
  const float* bv = (const float*)d_in[7];
  const float* wo = (const float*)d_in[8];
  const float* bo = (const float*)d_in[9];

  char* ws = (char*)d_ws;
  ushortT* hs_b = (ushortT*)(ws);                 // [4096][1024] bf16
  ushortT* wq_b = (ushortT*)(ws + (8u << 20));    // 4 weights bf16 (contiguous)
  ushortT* wk_b = wq_b + (1u << 20);
  ushortT* wv_b = wq_b + (2u << 20);
  ushortT* wo_b = wq_b + (3u << 20);
  ushortT* q_b  = (ushortT*)(ws + (16u << 20));   // [16][4096][64]
  ushortT* k_b  = (ushortT*)(ws + (24u << 20));   // [16][4096][64]
  ushortT* vt_b = (ushortT*)(ws + (32u << 20));   // [16][64][4096]
  ushortT* at_b = (ushortT*)(ws + (40u << 20));   // [4096][1024]
  float*   l2s  = (float*)(ws + (48u << 20));     // [4096]

  float* outp    = (float*)d_out;
  float* metricp = outp + (size_t)L_SEQ * EMBED;

  cast_bf16_k<<<L_SEQ * EMBED / 8 / 256, 256, 0, stream>>>(hs, hs_b, L_SEQ * EMBED / 8);
  cast4_bf16_k<<<2048, 256, 0, stream>>>(wq, wk, wv, wo, wq_b);
  l2size_k<<<L_SEQ / 256, 256, 0, stream>>>(sz, l2s, L_SEQ);

  GemmArgs aq{wq_b, bq, (void*)q_b, 0};
  GemmArgs ak{wk_b, bk, (void*)k_b, 1};
  GemmArgs av{wv_b, bv, (void*)vt_b, 2};
  gemm_bt_k<<<dim3(256, 3), 256, 0, stream>>>(hs_b, aq, ak, av);   // fused QKV

  metric_k<<<L_SEQ * 8 / 256, 256, 0, stream>>>(k_b, metricp);

  attn_k<<<1024, 256, 0, stream>>>(q_b, k_b, vt_b, l2s, at_b);

  GemmArgs ao{wo_b, bo, (void*)outp, 3};
  gemm_bt_k<<<dim3(256, 1), 256, 0, stream>>>(at_b, ao, ao, ao);   // O projection
}

// Round 11
// 242.370 us; speedup vs baseline: 1.6036x; 1.6036x over previous
//
#include <hip/hip_runtime.h>

// Problem: B=1, L=4096, EMBED=1024, 16 heads x 64
static constexpr int L_SEQ = 4096;
static constexpr int EMBED = 1024;
static constexpr int HEADS = 16;
static constexpr int HD    = 64;

typedef unsigned short ushortT;
typedef __attribute__((ext_vector_type(8)))  short short8;   // 8 x bf16 (4 VGPR)
typedef __attribute__((ext_vector_type(4)))  float f32x4;

#define LOG2E 1.4426950408889634f

__device__ __forceinline__ ushortT f2bf(float f) {
  unsigned u = __builtin_bit_cast(unsigned, f);
  u += 0x7fffu + ((u >> 16) & 1u);          // round-to-nearest-even
  return (ushortT)(u >> 16);
}
__device__ __forceinline__ float bf2f(ushortT s) {
  return __builtin_bit_cast(float, ((unsigned)s) << 16);
}

// ---- DPP 16-lane butterfly reduction (VALU pipe) ----
// ctrls: 0xB1 quad_perm xor1, 0x4E quad_perm xor2, 0x141 row_half_mirror
// (lane^7), 0x140 row_mirror (lane^15). After xor1+xor2 the partials are
// quad-uniform, so ^7 / ^15 deliver the same partner values as ^4 / ^8 ->
// bitwise-identical to the __shfl_xor(1,2,4,8) version.
template <int CTRL>
__device__ __forceinline__ float fmax_dpp(float x) {
  int v = __builtin_amdgcn_mov_dpp(__builtin_bit_cast(int, x), CTRL, 0xF, 0xF, true);
  return fmaxf(x, __builtin_bit_cast(float, v));
}
template <int CTRL>
__device__ __forceinline__ float fadd_dpp(float x) {
  int v = __builtin_amdgcn_mov_dpp(__builtin_bit_cast(int, x), CTRL, 0xF, 0xF, true);
  return x + __builtin_bit_cast(float, v);
}
__device__ __forceinline__ float red16_max(float x) {
  x = fmax_dpp<0xB1>(x); x = fmax_dpp<0x4E>(x);
  x = fmax_dpp<0x141>(x); x = fmax_dpp<0x140>(x);
  return x;
}
__device__ __forceinline__ float red16_sum(float x) {
  x = fadd_dpp<0xB1>(x); x = fadd_dpp<0x4E>(x);
  x = fadd_dpp<0x141>(x); x = fadd_dpp<0x140>(x);
  return x;
}

// async global->LDS, 16B/lane; LDS dest is wave-uniform base + lane*16.
#define GLOAD_LDS16(g, l) \
  __builtin_amdgcn_global_load_lds((const __attribute__((address_space(1))) void*)(g), \
                                   (__attribute__((address_space(3))) void*)(l), 16, 0, 0)

// ---------------- fp32 -> bf16 cast, 8 elems/thread ----------------
__global__ void cast_bf16_k(const float* __restrict__ in, ushortT* __restrict__ out, int n8) {
  int i = blockIdx.x * blockDim.x + threadIdx.x;
  if (i >= n8) return;
  const float4* p = (const float4*)in;
  float4 a = p[2 * i], b = p[2 * i + 1];
  uint4 o;
  o.x = (unsigned)f2bf(a.x) | ((unsigned)f2bf(a.y) << 16);
  o.y = (unsigned)f2bf(a.z) | ((unsigned)f2bf(a.w) << 16);
  o.z = (unsigned)f2bf(b.x) | ((unsigned)f2bf(b.y) << 16);
  o.w = (unsigned)f2bf(b.z) | ((unsigned)f2bf(b.w) << 16);
  ((uint4*)out)[i] = o;
}

// fused 4-weight cast (each weight 1M elements), dsts contiguous at out
__global__ void cast4_bf16_k(const float* __restrict__ a, const float* __restrict__ b,
                             const float* __restrict__ c, const float* __restrict__ d,
                             ushortT* __restrict__ out) {
  int idx = blockIdx.x * blockDim.x + threadIdx.x;   // 4 * 131072
  int w = idx >> 17, i = idx & 131071;
  const float* src = (w == 0) ? a : (w == 1) ? b : (w == 2) ? c : d;
  const float4* p = (const float4*)src;
  float4 x = p[2 * i], y = p[2 * i + 1];
  uint4 o;
  o.x = (unsigned)f2bf(x.x) | ((unsigned)f2bf(x.y) << 16);
  o.y = (unsigned)f2bf(x.z) | ((unsigned)f2bf(x.w) << 16);
  o.z = (unsigned)f2bf(y.x) | ((unsigned)f2bf(y.y) << 16);
  o.w = (unsigned)f2bf(y.z) | ((unsigned)f2bf(y.w) << 16);
  ((uint4*)(out + ((size_t)w << 20)))[i] = o;
}

// ---------------- log2(size) ----------------
__global__ void l2size_k(const float* __restrict__ sz, float* __restrict__ l2s, int n) {
  int i = blockIdx.x * blockDim.x + threadIdx.x;
  if (i < n) l2s[i] = __log2f(sz[i]);
}

// ---------------- GEMM: C[M,N] = A[M,K] @ B[N,K]^T + bias ----------------
struct GemmArgs { const ushortT* B; const float* bias; void* dst; int mode; };
// mode 0: Q -> bf16 [h][t][64] * 0.125   mode 1: K -> bf16 [h][t][64]
// mode 2: V -> bf16 [h][64][t] (transposed)      mode 3: fp32 [m][1024]

__global__ __launch_bounds__(256, 3) void gemm_bt_k(
    const ushortT* __restrict__ A, GemmArgs g0, GemmArgs g1, GemmArgs g2)
{
  constexpr int K = 1024;
  __shared__ __align__(16) ushortT As[128 * 64];
  __shared__ __align__(16) ushortT Bs[128 * 64];

  GemmArgs g = (blockIdx.y == 0) ? g0 : ((blockIdx.y == 1) ? g1 : g2);
  const ushortT* __restrict__ Bw = g.B;

  const int tid = threadIdx.x;
  const int wv = tid >> 6, ln = tid & 63;
  const int mb = blockIdx.x & 31, nb = blockIdx.x >> 5;     // 32 x 8 blocks
  const int m0 = mb * 128, n0 = nb * 128;
  const int wr = wv >> 1, wc = wv & 1;
  const int lrow = ln & 15, lq = ln >> 4;

  const int rstg = wv * 8 + (ln >> 3);
  const int ustg = (ln & 7) ^ (ln >> 3);

  f32x4 acc[4][4] = {};

  for (int kt = 0; kt < K; kt += 64) {
#pragma unroll
    for (int i = 0; i < 4; ++i) {
      int r = i * 32 + rstg;
      GLOAD_LDS16(A  + (size_t)(m0 + r) * K + kt + (ustg << 3), As + i * 2048 + wv * 512);
      GLOAD_LDS16(Bw + (size_t)(n0 + r) * K + kt + (ustg << 3), Bs + i * 2048 + wv * 512);
    }
    __syncthreads();
#pragma unroll
    for (int ks = 0; ks < 2; ++ks) {
      short8 a[4], b[4];
#pragma unroll
      for (int mi = 0; mi < 4; ++mi) {
        int ra = wr * 64 + mi * 16 + lrow;
        int u = (ks * 4 + lq) ^ (ra & 7);
        a[mi] = *(const short8*)(As + ra * 64 + (u << 3));
      }
#pragma unroll
      for (int ni = 0; ni < 4; ++ni) {
        int rb = wc * 64 + ni * 16 + lrow;
        int u = (ks * 4 + lq) ^ (rb & 7);
        b[ni] = *(const short8*)(Bs + rb * 64 + (u << 3));
      }
#pragma unroll
      for (int mi = 0; mi < 4; ++mi)
#pragma unroll
        for (int ni = 0; ni < 4; ++ni)
          acc[mi][ni] = __builtin_amdgcn_mfma_f32_16x16x32_bf16(a[mi], b[ni], acc[mi][ni], 0, 0, 0);
    }
    __syncthreads();
  }

  const int mode = g.mode;
  if (mode <= 1) {
    ushortT* dst = (ushortT*)g.dst;
    const float sc = (mode == 0) ? 0.125f : 1.0f;
#pragma unroll
    for (int ni = 0; ni < 4; ++ni) {
      int n = n0 + wc * 64 + ni * 16 + lrow;
      float bsv = g.bias[n];
      size_t base = ((size_t)(n >> 6) * L_SEQ) * HD + (n & 63);
#pragma unroll
      for (int mi = 0; mi < 4; ++mi)
#pragma unroll
        for (int r = 0; r < 4; ++r) {
          int m = m0 + wr * 64 + mi * 16 + lq * 4 + r;
          dst[base + (size_t)m * HD] = f2bf((acc[mi][ni][r] + bsv) * sc);
        }
    }
  } else if (mode == 2) {
    ushortT* dst = (ushortT*)g.dst;
#pragma unroll
    for (int ni = 0; ni < 4; ++ni) {
      int n = n0 + wc * 64 + ni * 16 + lrow;     // n == h*64+hd
      float bsv = g.bias[n];
      size_t base = (size_t)n * L_SEQ;
#pragma unroll
      for (int mi = 0; mi < 4; ++mi)
#pragma unroll
        for (int r = 0; r < 4; ++r) {
          int m = m0 + wr * 64 + mi * 16 + lq * 4 + r;
          dst[base + m] = f2bf(acc[mi][ni][r] + bsv);
        }
    }
  } else {
    float* dst = (float*)g.dst;
#pragma unroll
    for (int ni = 0; ni < 4; ++ni) {
      int n = n0 + wc * 64 + ni * 16 + lrow;
      float bsv = g.bias[n];
#pragma unroll
      for (int mi = 0; mi < 4; ++mi)
#pragma unroll
        for (int r = 0; r < 4; ++r) {
          int m = m0 + wr * 64 + mi * 16 + lq * 4 + r;
          dst[(size_t)m * EMBED + n] = acc[mi][ni][r] + bsv;
        }
    }
  }
}

// ---------------- flash attention (16x16 + K/V double-buffer, 1 barrier/tile) --
// 1024 blocks, XCD head-clustering swizzle (FETCH 70->12MB). Softmax via DPP
// butterfly (R9). NEW (R11): K/V double-buffered via global_load_lds with the
// stage of tile t+1 issued BEFORE compute of tile t, ONE barrier per tile
// (compiler's pre-barrier vmcnt(0) drain = race-free, m97 pattern). To keep
// 4 blocks/CU the P buffer is compressed 72->64 stride with a 16B-slot XOR
// swizzle (slot ^= q&7, bijective per row -> bitwise-identical): total LDS
// = 2*(8K+8K) + 8K = 40960 B exactly = 163840/4.
__global__ __launch_bounds__(256, 4) void attn_k(
    const ushortT* __restrict__ Q,   // [16][4096][64], pre-scaled by 0.125
    const ushortT* __restrict__ Kb,  // [16][4096][64]
    const ushortT* __restrict__ Vt,  // [16][64][4096]
    const float*   __restrict__ l2s, // [4096] log2(size)
    ushortT* __restrict__ O)         // [4096][1024] bf16
{
  __shared__ __align__(16) ushortT Ks[2][64 * 64];
  __shared__ __align__(16) ushortT Vs[2][64 * 64];
  __shared__ __align__(16) ushortT Ps[4][16 * 64];  // slot-XOR swizzled

  const int id = blockIdx.x;                 // 0..1023
  const int xcd = id & 7, s = id >> 3;
  const int h  = xcd * 2 + (s >> 6);         // head (2 per XCD)
  const int q0 = (s & 63) * 64;              // q-tile base

  const int tid = threadIdx.x;
  const int wv = tid >> 6, ln = tid & 63;
  const int lrow = ln & 15, lq = ln >> 4;

  short8 qf0, qf1;  // hoisted Q A-fragments (row = lane&15, k contiguous)
  {
    const ushortT* qp = Q + ((size_t)h * L_SEQ + q0 + wv * 16 + lrow) * HD + lq * 8;
    qf0 = *(const short8*)qp;
    qf1 = *(const short8*)(qp + 32);
  }

  f32x4 o[4] = {};
  float mrun[4], lrun[4];
#pragma unroll
  for (int r = 0; r < 4; ++r) { mrun[r] = -1e30f; lrun[r] = 0.f; }

  const int rstg = wv * 8 + (ln >> 3);
  const int ustg = (ln & 7) ^ (ln >> 3);

  auto STAGE = [&](int buf, int t0) {
#pragma unroll
    for (int i = 0; i < 2; ++i) {
      int r = i * 32 + rstg;
      GLOAD_LDS16(Kb + ((size_t)h * L_SEQ + t0 + r) * HD + (ustg << 3), &Ks[buf][i * 2048 + wv * 512]);
      GLOAD_LDS16(Vt + ((size_t)(h * HD + r)) * L_SEQ + t0 + (ustg << 3), &Vs[buf][i * 2048 + wv * 512]);
    }
  };

  STAGE(0, 0);
  __syncthreads();                   // tile 0 resident

  constexpr int NT = L_SEQ / 64;
#pragma unroll 1
  for (int t = 0; t < NT; ++t) {
    const int cur = t & 1;
    if (t + 1 < NT) STAGE(cur ^ 1, (t + 1) * 64);   // overlaps entire compute
    const int t0 = t * 64;
    const ushortT* Kt  = &Ks[cur][0];
    const ushortT* Vtl = &Vs[cur][0];

    // S = Q K^T  (rows q, cols key)
    f32x4 sfr[4] = {};
    __builtin_amdgcn_s_setprio(1);
#pragma unroll
    for (int ks = 0; ks < 2; ++ks) {
      short8 qa = ks ? qf1 : qf0;
#pragma unroll
      for (int f = 0; f < 4; ++f) {
        int key = f * 16 + lrow;
        int u = (ks * 4 + lq) ^ (key & 7);
        short8 kb = *(const short8*)(Kt + key * 64 + (u << 3));
        sfr[f] = __builtin_amdgcn_mfma_f32_16x16x32_bf16(qa, kb, sfr[f], 0, 0, 0);
      }
    }
    __builtin_amdgcn_s_setprio(0);

    // base-2 logits + log2(size_key)
#pragma unroll
    for (int f = 0; f < 4; ++f) {
      float bias = l2s[t0 + f * 16 + lrow];
#pragma unroll
      for (int r = 0; r < 4; ++r)
        sfr[f][r] = sfr[f][r] * LOG2E + bias;
    }

    // online softmax; row r lives in 16-lane group (lanes share lq)
    float alpha[4];
    bool noop = true;
#pragma unroll
    for (int r = 0; r < 4; ++r) {
      float t1 = fmaxf(fmaxf(sfr[0][r], sfr[1][r]), fmaxf(sfr[2][r], sfr[3][r]));
      t1 = red16_max(t1);                        // DPP butterfly (VALU pipe)
      float mnew = fmaxf(mrun[r], t1);
      alpha[r] = __builtin_amdgcn_exp2f(mrun[r] - mnew);
      mrun[r] = mnew;
      float rs = 0.f;
#pragma unroll
      for (int f = 0; f < 4; ++f) {
        float pv = __builtin_amdgcn_exp2f(sfr[f][r] - mnew);
        sfr[f][r] = pv;
        rs += pv;
      }
      rs = red16_sum(rs);                        // DPP butterfly (VALU pipe)
      lrun[r] = lrun[r] * alpha[r] + rs;
      noop = noop && (alpha[r] == 1.0f);
    }
    if (!__all(noop)) {              // skip O-rescale when all alphas == 1
#pragma unroll
      for (int df = 0; df < 4; ++df)
#pragma unroll
        for (int r = 0; r < 4; ++r) o[df][r] *= alpha[r];
    }

    // P -> per-wave LDS, 64-stride + 16B-slot XOR swizzle (slot ^= q&7)
    ushortT* pb = &Ps[wv][0];
#pragma unroll
    for (int f = 0; f < 4; ++f)
#pragma unroll
      for (int r = 0; r < 4; ++r) {
        int q = lq * 4 + r;
        int slot = (f * 2 + (lrow >> 3)) ^ (q & 7);
        pb[q * 64 + slot * 8 + (lrow & 7)] = f2bf(sfr[f][r]);
      }

    asm volatile("s_waitcnt lgkmcnt(0)" ::: "memory");  // cross-lane LDS dep
    __builtin_amdgcn_sched_barrier(0);

    short8 pa0 = *(const short8*)(pb + lrow * 64 + ((lq ^ (lrow & 7)) << 3));
    short8 pa1 = *(const short8*)(pb + lrow * 64 + (((4 + lq) ^ (lrow & 7)) << 3));

    // O += P @ V   (B operand from transposed-V tile: row=d, k=key)
    __builtin_amdgcn_s_setprio(1);
#pragma unroll
    for (int ks = 0; ks < 2; ++ks) {
      short8 pa = ks ? pa1 : pa0;
#pragma unroll
      for (int df = 0; df < 4; ++df) {
        int d = df * 16 + lrow;
        int u = (ks * 4 + lq) ^ (d & 7);
        short8 vb = *(const short8*)(Vtl + d * 64 + (u << 3));
        o[df] = __builtin_amdgcn_mfma_f32_16x16x32_bf16(pa, vb, o[df], 0, 0, 0);
      }
    }
    __builtin_amdgcn_s_setprio(0);

    __syncthreads();                 // drains next-tile loads; frees cur buffer
  }

  // epilogue: divide by softmax denom, store bf16 [t][h*64+d]
#pragma unroll
  for (int df = 0; df < 4; ++df)
#pragma unroll
    for (int r = 0; r < 4; ++r) {
      int q = q0 + wv * 16 + lq * 4 + r;
      O[(size_t)q * EMBED + h * HD + df * 16 + lrow] = f2bf(o[df][r] / lrun[r]);
    }
}

// ---------------- metric = mean over heads of K ----------------
__global__ void metric_k(const ushortT* __restrict__ Kb, float* __restrict__ out) {
  int idx = blockIdx.x * blockDim.x + threadIdx.x;   // t*8 + c8
  int t = idx >> 3, c8 = idx & 7;
  float acc[8] = {};
#pragma unroll
  for (int h = 0; h < HEADS; ++h) {
    short8 v = *(const short8*)(Kb + ((size_t)h * L_SEQ + t) * HD + c8 * 8);
#pragma unroll
    for (int j = 0; j < 8; ++j) acc[j] += bf2f((ushortT)v[j]);
  }
  float* dst = out + (size_t)t * HD + c8 * 8;
#pragma unroll
  for (int j = 0; j < 8; ++j) dst[j] = acc[j] * (1.0f / 16.0f);
}

extern "C" void kernel_launch(void* const* d_in, const int* in_sizes, int n_in,
                              void* d_out, int out_size, void* d_ws, size_t ws_size,
                              hipStream_t stream) {
  const float* hs = (const float*)d_in[0];
  const float* sz = (const float*)d_in[1];
  const float* wq = (const float*)d_in[2];
  const float* bq = (const float*)d_in[3];
  const float* wk = (const float*)d_in[4];
  const float* bk = (const float*)d_in[5];
  const float* wv = (const float*)d_in[6];
  const float* bv = (const float*)d_in[7];
  const float* wo = (const float*)d_in[8];
  const float* bo = (const float*)d_in[9];

  char* ws = (char*)d_ws;
  ushortT* hs_b = (ushortT*)(ws);                 // [4096][1024] bf16
  ushortT* wq_b = (ushortT*)(ws + (8u << 20));    // 4 weights bf16 (contiguous)
  ushortT* wk_b = wq_b + (1u << 20);
  ushortT* wv_b = wq_b + (2u << 20);
  ushortT* wo_b = wq_b + (3u << 20);
  ushortT* q_b  = (ushortT*)(ws + (16u << 20));   // [16][4096][64]
  ushortT* k_b  = (ushortT*)(ws + (24u << 20));   // [16][4096][64]
  ushortT* vt_b = (ushortT*)(ws + (32u << 20));   // [16][64][4096]
  ushortT* at_b = (ushortT*)(ws + (40u << 20));   // [4096][1024]
  float*   l2s  = (float*)(ws + (48u << 20));     // [4096]

  float* outp    = (float*)d_out;
  float* metricp = outp + (size_t)L_SEQ * EMBED;

  cast_bf16_k<<<L_SEQ * EMBED / 8 / 256, 256, 0, stream>>>(hs, hs_b, L_SEQ * EMBED / 8);
  cast4_bf16_k<<<2048, 256, 0, stream>>>(wq, wk, wv, wo, wq_b);
  l2size_k<<<L_SEQ / 256, 256, 0, stream>>>(sz, l2s, L_SEQ);

  GemmArgs aq{wq_b, bq, (void*)q_b, 0};
  GemmArgs ak{wk_b, bk, (void*)k_b, 1};
  GemmArgs av{wv_b, bv, (void*)vt_b, 2};
  gemm_bt_k<<<dim3(256, 3), 256, 0, stream>>>(hs_b, aq, ak, av);   // fused QKV

  metric_k<<<L_SEQ * 8 / 256, 256, 0, stream>>>(k_b, metricp);

  attn_k<<<1024, 256, 0, stream>>>(q_b, k_b, vt_b, l2s, at_b);

  GemmArgs ao{wo_b, bo, (void*)outp, 3};
  gemm_bt_k<<<dim3(256, 1), 256, 0, stream>>>(at_b, ao, ao, ao);   // O projection
}

// Round 14
// 235.297 us; speedup vs baseline: 1.6518x; 1.0301x over previous
//
#include <hip/hip_runtime.h>

// Problem: B=1, L=4096, EMBED=1024, 16 heads x 64
static constexpr int L_SEQ = 4096;
static constexpr int EMBED = 1024;
static constexpr int HEADS = 16;
static constexpr int HD    = 64;

typedef unsigned short ushortT;
typedef __attribute__((ext_vector_type(8)))  short short8;   // 8 x bf16 (4 VGPR)
typedef __attribute__((ext_vector_type(4)))  float f32x4;

#define LOG2E 1.4426950408889634f

__device__ __forceinline__ ushortT f2bf(float f) {
  unsigned u = __builtin_bit_cast(unsigned, f);
  u += 0x7fffu + ((u >> 16) & 1u);          // round-to-nearest-even
  return (ushortT)(u >> 16);
}
__device__ __forceinline__ float bf2f(ushortT s) {
  return __builtin_bit_cast(float, ((unsigned)s) << 16);
}

// ---- DPP 16-lane butterfly reduction (VALU pipe) ----
// ctrls: 0xB1 quad_perm xor1, 0x4E quad_perm xor2, 0x141 row_half_mirror
// (lane^7), 0x140 row_mirror (lane^15). After xor1+xor2 the partials are
// quad-uniform, so ^7 / ^15 deliver the same partner values as ^4 / ^8 ->
// bitwise-identical to the __shfl_xor(1,2,4,8) version.
template <int CTRL>
__device__ __forceinline__ float fmax_dpp(float x) {
  int v = __builtin_amdgcn_mov_dpp(__builtin_bit_cast(int, x), CTRL, 0xF, 0xF, true);
  return fmaxf(x, __builtin_bit_cast(float, v));
}
template <int CTRL>
__device__ __forceinline__ float fadd_dpp(float x) {
  int v = __builtin_amdgcn_mov_dpp(__builtin_bit_cast(int, x), CTRL, 0xF, 0xF, true);
  return x + __builtin_bit_cast(float, v);
}
__device__ __forceinline__ float red16_max(float x) {
  x = fmax_dpp<0xB1>(x); x = fmax_dpp<0x4E>(x);
  x = fmax_dpp<0x141>(x); x = fmax_dpp<0x140>(x);
  return x;
}
__device__ __forceinline__ float red16_sum(float x) {
  x = fadd_dpp<0xB1>(x); x = fadd_dpp<0x4E>(x);
  x = fadd_dpp<0x141>(x); x = fadd_dpp<0x140>(x);
  return x;
}

// async global->LDS, 16B/lane; LDS dest is wave-uniform base + lane*16.
#define GLOAD_LDS16(g, l) \
  __builtin_amdgcn_global_load_lds((const __attribute__((address_space(1))) void*)(g), \
                                   (__attribute__((address_space(3))) void*)(l), 16, 0, 0)

// ---------------- fp32 -> bf16 cast, 8 elems/thread ----------------
__global__ void cast_bf16_k(const float* __restrict__ in, ushortT* __restrict__ out, int n8) {
  int i = blockIdx.x * blockDim.x + threadIdx.x;
  if (i >= n8) return;
  const float4* p = (const float4*)in;
  float4 a = p[2 * i], b = p[2 * i + 1];
  uint4 o;
  o.x = (unsigned)f2bf(a.x) | ((unsigned)f2bf(a.y) << 16);
  o.y = (unsigned)f2bf(a.z) | ((unsigned)f2bf(a.w) << 16);
  o.z = (unsigned)f2bf(b.x) | ((unsigned)f2bf(b.y) << 16);
  o.w = (unsigned)f2bf(b.z) | ((unsigned)f2bf(b.w) << 16);
  ((uint4*)out)[i] = o;
}

// fused 4-weight cast (each weight 1M elements), dsts contiguous at out
__global__ void cast4_bf16_k(const float* __restrict__ a, const float* __restrict__ b,
                             const float* __restrict__ c, const float* __restrict__ d,
                             ushortT* __restrict__ out) {
  int idx = blockIdx.x * blockDim.x + threadIdx.x;   // 4 * 131072
  int w = idx >> 17, i = idx & 131071;
  const float* src = (w == 0) ? a : (w == 1) ? b : (w == 2) ? c : d;
  const float4* p = (const float4*)src;
  float4 x = p[2 * i], y = p[2 * i + 1];
  uint4 o;
  o.x = (unsigned)f2bf(x.x) | ((unsigned)f2bf(x.y) << 16);
  o.y = (unsigned)f2bf(x.z) | ((unsigned)f2bf(x.w) << 16);
  o.z = (unsigned)f2bf(y.x) | ((unsigned)f2bf(y.y) << 16);
  o.w = (unsigned)f2bf(y.z) | ((unsigned)f2bf(y.w) << 16);
  ((uint4*)(out + ((size_t)w << 20)))[i] = o;
}

// ---------------- log2(size) ----------------
__global__ void l2size_k(const float* __restrict__ sz, float* __restrict__ l2s, int n) {
  int i = blockIdx.x * blockDim.x + threadIdx.x;
  if (i < n) l2s[i] = __log2f(sz[i]);
}

// ---------------- GEMM: C[M,N] = A[M,K] @ B[N,K]^T + bias ----------------
struct GemmArgs { const ushortT* B; const float* bias; void* dst; int mode; };
// mode 0: Q -> bf16 [h][t][64] * 0.125   mode 1: K -> bf16 [h][t][64]
// mode 2: V -> bf16 [h][64][t] (transposed)      mode 3: fp32 [m][1024]

__global__ __launch_bounds__(256, 3) void gemm_bt_k(
    const ushortT* __restrict__ A, GemmArgs g0, GemmArgs g1, GemmArgs g2)
{
  constexpr int K = 1024;
  __shared__ __align__(16) ushortT As[128 * 64];
  __shared__ __align__(16) ushortT Bs[128 * 64];

  GemmArgs g = (blockIdx.y == 0) ? g0 : ((blockIdx.y == 1) ? g1 : g2);
  const ushortT* __restrict__ Bw = g.B;

  const int tid = threadIdx.x;
  const int wv = tid >> 6, ln = tid & 63;
  // XCD-locality decode (T1): nb = id&7 so each XCD serves ONE 128-col
  // B-panel (256KB, L2-resident) assuming hw round-robin xcd = id%8.
  const int nb = blockIdx.x & 7, mb = blockIdx.x >> 3;      // 8 x 32 blocks
  const int m0 = mb * 128, n0 = nb * 128;
  const int wr = wv >> 1, wc = wv & 1;
  const int lrow = ln & 15, lq = ln >> 4;

  const int rstg = wv * 8 + (ln >> 3);
  const int ustg = (ln & 7) ^ (ln >> 3);

  f32x4 acc[4][4] = {};

  for (int kt = 0; kt < K; kt += 64) {
#pragma unroll
    for (int i = 0; i < 4; ++i) {
      int r = i * 32 + rstg;
      GLOAD_LDS16(A  + (size_t)(m0 + r) * K + kt + (ustg << 3), As + i * 2048 + wv * 512);
      GLOAD_LDS16(Bw + (size_t)(n0 + r) * K + kt + (ustg << 3), Bs + i * 2048 + wv * 512);
    }
    __syncthreads();
#pragma unroll
    for (int ks = 0; ks < 2; ++ks) {
      short8 a[4], b[4];
#pragma unroll
      for (int mi = 0; mi < 4; ++mi) {
        int ra = wr * 64 + mi * 16 + lrow;
        int u = (ks * 4 + lq) ^ (ra & 7);
        a[mi] = *(const short8*)(As + ra * 64 + (u << 3));
      }
#pragma unroll
      for (int ni = 0; ni < 4; ++ni) {
        int rb = wc * 64 + ni * 16 + lrow;
        int u = (ks * 4 + lq) ^ (rb & 7);
        b[ni] = *(const short8*)(Bs + rb * 64 + (u << 3));
      }
#pragma unroll
      for (int mi = 0; mi < 4; ++mi)
#pragma unroll
        for (int ni = 0; ni < 4; ++ni)
          acc[mi][ni] = __builtin_amdgcn_mfma_f32_16x16x32_bf16(a[mi], b[ni], acc[mi][ni], 0, 0, 0);
    }
    __syncthreads();
  }

  const int mode = g.mode;
  if (mode <= 1) {
    ushortT* dst = (ushortT*)g.dst;
    const float sc = (mode == 0) ? 0.125f : 1.0f;
#pragma unroll
    for (int ni = 0; ni < 4; ++ni) {
      int n = n0 + wc * 64 + ni * 16 + lrow;
      float bsv = g.bias[n];
      size_t base = ((size_t)(n >> 6) * L_SEQ) * HD + (n & 63);
#pragma unroll
      for (int mi = 0; mi < 4; ++mi)
#pragma unroll
        for (int r = 0; r < 4; ++r) {
          int m = m0 + wr * 64 + mi * 16 + lq * 4 + r;
          dst[base + (size_t)m * HD] = f2bf((acc[mi][ni][r] + bsv) * sc);
        }
    }
  } else if (mode == 2) {
    ushortT* dst = (ushortT*)g.dst;
#pragma unroll
    for (int ni = 0; ni < 4; ++ni) {
      int n = n0 + wc * 64 + ni * 16 + lrow;     // n == h*64+hd
      float bsv = g.bias[n];
      size_t base = (size_t)n * L_SEQ;
#pragma unroll
      for (int mi = 0; mi < 4; ++mi)
#pragma unroll
        for (int r = 0; r < 4; ++r) {
          int m = m0 + wr * 64 + mi * 16 + lq * 4 + r;
          dst[base + m] = f2bf(acc[mi][ni][r] + bsv);
        }
    }
  } else {
    float* dst = (float*)g.dst;
#pragma unroll
    for (int ni = 0; ni < 4; ++ni) {
      int n = n0 + wc * 64 + ni * 16 + lrow;
      float bsv = g.bias[n];
#pragma unroll
      for (int mi = 0; mi < 4; ++mi)
#pragma unroll
        for (int r = 0; r < 4; ++r) {
          int m = m0 + wr * 64 + mi * 16 + lq * 4 + r;
          dst[(size_t)m * EMBED + n] = acc[mi][ni][r] + bsv;
        }
    }
  }
}

// ---------------- flash attention (R9: 16x16, single-buffer, DPP softmax) ----
// 1024 blocks, XCD head-clustering swizzle (FETCH 70->12MB, R7). Softmax
// reductions via DPP butterfly on the VALU pipe (R9, -25%). Single-buffered
// K/V (R6 proved dbuf's LDS cost drops occupancy; R10 proved reg-prefetch
// spills; R11 proved swizzled dbuf trades VALU for LDS at a loss; R12/R13's
// tr_b16 path failed layout verification). O-rescale skipped when all
// alphas == 1.0 (bitwise-identical).
__global__ __launch_bounds__(256, 4) void attn_k(
    const ushortT* __restrict__ Q,   // [16][4096][64], pre-scaled by 0.125
    const ushortT* __restrict__ Kb,  // [16][4096][64]
    const ushortT* __restrict__ Vt,  // [16][64][4096]
    const float*   __restrict__ l2s, // [4096] log2(size)
    ushortT* __restrict__ O)         // [4096][1024] bf16
{
  __shared__ __align__(16) ushortT Ks[64 * 64];
  __shared__ __align__(16) ushortT Vs[64 * 64];
  __shared__ __align__(16) ushortT Ps[4][16 * 72];  // per-wave, +8 pad

  const int id = blockIdx.x;                 // 0..1023
  const int xcd = id & 7, s = id >> 3;
  const int h  = xcd * 2 + (s >> 6);         // head (2 per XCD)
  const int q0 = (s & 63) * 64;              // q-tile base

  const int tid = threadIdx.x;
  const int wv = tid >> 6, ln = tid & 63;
  const int lrow = ln & 15, lq = ln >> 4;

  short8 qf0, qf1;  // hoisted Q A-fragments (row = lane&15, k contiguous)
  {
    const ushortT* qp = Q + ((size_t)h * L_SEQ + q0 + wv * 16 + lrow) * HD + lq * 8;
    qf0 = *(const short8*)qp;
    qf1 = *(const short8*)(qp + 32);
  }

  f32x4 o[4] = {};
  float mrun[4], lrun[4];
#pragma unroll
  for (int r = 0; r < 4; ++r) { mrun[r] = -1e30f; lrun[r] = 0.f; }

  const int rstg = wv * 8 + (ln >> 3);
  const int ustg = (ln & 7) ^ (ln >> 3);

  for (int t = 0; t < L_SEQ / 64; ++t) {
    const int t0 = t * 64;
#pragma unroll
    for (int i = 0; i < 2; ++i) {
      int r = i * 32 + rstg;
      GLOAD_LDS16(Kb + ((size_t)h * L_SEQ + t0 + r) * HD + (ustg << 3), Ks + i * 2048 + wv * 512);
      GLOAD_LDS16(Vt + ((size_t)(h * HD + r)) * L_SEQ + t0 + (ustg << 3), Vs + i * 2048 + wv * 512);
    }
    __syncthreads();

    // S = Q K^T  (rows q, cols key)
    f32x4 sfr[4] = {};
    __builtin_amdgcn_s_setprio(1);
#pragma unroll
    for (int ks = 0; ks < 2; ++ks) {
      short8 qa = ks ? qf1 : qf0;
#pragma unroll
      for (int f = 0; f < 4; ++f) {
        int key = f * 16 + lrow;
        int u = (ks * 4 + lq) ^ (key & 7);
        short8 kb = *(const short8*)(Ks + key * 64 + (u << 3));
        sfr[f] = __builtin_amdgcn_mfma_f32_16x16x32_bf16(qa, kb, sfr[f], 0, 0, 0);
      }
    }
    __builtin_amdgcn_s_setprio(0);

    // base-2 logits + log2(size_key)
#pragma unroll
    for (int f = 0; f < 4; ++f) {
      float bias = l2s[t0 + f * 16 + lrow];
#pragma unroll
      for (int r = 0; r < 4; ++r)
        sfr[f][r] = sfr[f][r] * LOG2E + bias;
    }

    // online softmax; row r lives in 16-lane group (lanes share lq)
    float alpha[4];
    bool noop = true;
#pragma unroll
    for (int r = 0; r < 4; ++r) {
      float t1 = fmaxf(fmaxf(sfr[0][r], sfr[1][r]), fmaxf(sfr[2][r], sfr[3][r]));
      t1 = red16_max(t1);                        // DPP butterfly (VALU pipe)
      float mnew = fmaxf(mrun[r], t1);
      alpha[r] = __builtin_amdgcn_exp2f(mrun[r] - mnew);
      mrun[r] = mnew;
      float rs = 0.f;
#pragma unroll
      for (int f = 0; f < 4; ++f) {
        float pv = __builtin_amdgcn_exp2f(sfr[f][r] - mnew);
        sfr[f][r] = pv;
        rs += pv;
      }
      rs = red16_sum(rs);                        // DPP butterfly (VALU pipe)
      lrun[r] = lrun[r] * alpha[r] + rs;
      noop = noop && (alpha[r] == 1.0f);
    }
    if (!__all(noop)) {              // skip O-rescale when all alphas == 1
#pragma unroll
      for (int df = 0; df < 4; ++df)
#pragma unroll
        for (int r = 0; r < 4; ++r) o[df][r] *= alpha[r];
    }

    // P -> per-wave LDS (C layout in, A layout out), padded to 72 shorts/row
    ushortT* pb = &Ps[wv][0];
#pragma unroll
    for (int f = 0; f < 4; ++f)
#pragma unroll
      for (int r = 0; r < 4; ++r)
        pb[(lq * 4 + r) * 72 + f * 16 + lrow] = f2bf(sfr[f][r]);

    asm volatile("s_waitcnt lgkmcnt(0)" ::: "memory");  // cross-lane LDS dep
    __builtin_amdgcn_sched_barrier(0);

    short8 pa0 = *(const short8*)(pb + lrow * 72 + lq * 8);
    short8 pa1 = *(const short8*)(pb + lrow * 72 + 32 + lq * 8);

    // O += P @ V   (B operand from transposed-V tile: row=d, k=key)
    __builtin_amdgcn_s_setprio(1);
#pragma unroll
    for (int ks = 0; ks < 2; ++ks) {
      short8 pa = ks ? pa1 : pa0;
#pragma unroll
      for (int df = 0; df < 4; ++df) {
        int d = df * 16 + lrow;
        int u = (ks * 4 + lq) ^ (d & 7);
        short8 vb = *(const short8*)(Vs + d * 64 + (u << 3));
        o[df] = __builtin_amdgcn_mfma_f32_16x16x32_bf16(pa, vb, o[df], 0, 0, 0);
      }
    }
    __builtin_amdgcn_s_setprio(0);

    __syncthreads();
  }

  // epilogue: divide by softmax denom, store bf16 [t][h*64+d]
#pragma unroll
  for (int df = 0; df < 4; ++df)
#pragma unroll
    for (int r = 0; r < 4; ++r) {
      int q = q0 + wv * 16 + lq * 4 + r;
      O[(size_t)q * EMBED + h * HD + df * 16 + lrow] = f2bf(o[df][r] / lrun[r]);
    }
}

// ---------------- metric = mean over heads of K ----------------
__global__ void metric_k(const ushortT* __restrict__ Kb, float* __restrict__ out) {
  int idx = blockIdx.x * blockDim.x + threadIdx.x;   // t*8 + c8
  int t = idx >> 3, c8 = idx & 7;
  float acc[8] = {};
#pragma unroll
  for (int h = 0; h < HEADS; ++h) {
    short8 v = *(const short8*)(Kb + ((size_t)h * L_SEQ + t) * HD + c8 * 8);
#pragma unroll
    for (int j = 0; j < 8; ++j) acc[j] += bf2f((ushortT)v[j]);
  }
  float* dst = out + (size_t)t * HD + c8 * 8;
#pragma unroll
  for (int j = 0; j < 8; ++j) dst[j] = acc[j] * (1.0f / 16.0f);
}

extern "C" void kernel_launch(void* const* d_in, const int* in_sizes, int n_in,
                              void* d_out, int out_size, void* d_ws, size_t ws_size,
                              hipStream_t stream) {
  const float* hs = (const float*)d_in[0];
  const float* sz = (const float*)d_in[1];
  const float* wq = (const float*)d_in[2];
  const float* bq = (const float*)d_in[3];
  const float* wk = (const float*)d_in[4];
  const float* bk = (const float*)d_in[5];
  const float* wv = (const float*)d_in[6];
  const float* bv = (const float*)d_in[7];
  const float* wo = (const float*)d_in[8];
  const float* bo = (const float*)d_in[9];

  char* ws = (char*)d_ws;
  ushortT* hs_b = (ushortT*)(ws);                 // [4096][1024] bf16
  ushortT* wq_b = (ushortT*)(ws + (8u << 20));    // 4 weights bf16 (contiguous)
  ushortT* wk_b = wq_b + (1u << 20);
  ushortT* wv_b = wq_b + (2u << 20);
  ushortT* wo_b = wq_b + (3u << 20);
  ushortT* q_b  = (ushortT*)(ws + (16u << 20));   // [16][4096][64]
  ushortT* k_b  = (ushortT*)(ws + (24u << 20));   // [16][4096][64]
  ushortT* vt_b = (ushortT*)(ws + (32u << 20));   // [16][64][4096]
  ushortT* at_b = (ushortT*)(ws + (40u << 20));   // [4096][1024]
  float*   l2s  = (float*)(ws + (48u << 20));     // [4096]

  float* outp    = (float*)d_out;
  float* metricp = outp + (size_t)L_SEQ * EMBED;

  cast_bf16_k<<<L_SEQ * EMBED / 8 / 256, 256, 0, stream>>>(hs, hs_b, L_SEQ * EMBED / 8);
  cast4_bf16_k<<<2048, 256, 0, stream>>>(wq, wk, wv, wo, wq_b);
  l2size_k<<<L_SEQ / 256, 256, 0, stream>>>(sz, l2s, L_SEQ);

  GemmArgs aq{wq_b, bq, (void*)q_b, 0};
  GemmArgs ak{wk_b, bk, (void*)k_b, 1};
  GemmArgs av{wv_b, bv, (void*)vt_b, 2};
  gemm_bt_k<<<dim3(256, 3), 256, 0, stream>>>(hs_b, aq, ak, av);   // fused QKV

  metric_k<<<L_SEQ * 8 / 256, 256, 0, stream>>>(k_b, metricp);

  attn_k<<<1024, 256, 0, stream>>>(q_b, k_b, vt_b, l2s, at_b);

  GemmArgs ao{wo_b, bo, (void*)outp, 3};
  gemm_bt_k<<<dim3(256, 1), 256, 0, stream>>>(at_b, ao, ao, ao);   // O projection
}

// Round 15
// 216.681 us; speedup vs baseline: 1.7937x; 1.0859x over previous
//
#include <hip/hip_runtime.h>

// Problem: B=1, L=4096, EMBED=1024, 16 heads x 64
static constexpr int L_SEQ = 4096;
static constexpr int EMBED = 1024;
static constexpr int HEADS = 16;
static constexpr int HD    = 64;

typedef unsigned short ushortT;
typedef __attribute__((ext_vector_type(8)))  short short8;   // 8 x bf16 (4 VGPR)
typedef __attribute__((ext_vector_type(4)))  float f32x4;
typedef __attribute__((ext_vector_type(4)))  unsigned uint4v;

#define LOG2E 1.4426950408889634f

__device__ __forceinline__ ushortT f2bf(float f) {
  unsigned u = __builtin_bit_cast(unsigned, f);
  u += 0x7fffu + ((u >> 16) & 1u);          // round-to-nearest-even
  return (ushortT)(u >> 16);
}
__device__ __forceinline__ float bf2f(ushortT s) {
  return __builtin_bit_cast(float, ((unsigned)s) << 16);
}
// v_cvt_pk_bf16_f32: two f32 -> u32 of 2x bf16 (lo=a, hi=b), RNE on CDNA4
__device__ __forceinline__ unsigned cvtpk(float a, float b) {
  unsigned r;
  asm("v_cvt_pk_bf16_f32 %0, %1, %2" : "=v"(r) : "v"(a), "v"(b));
  return r;
}

// async global->LDS, 16B/lane; LDS dest is wave-uniform base + lane*16.
#define GLOAD_LDS16(g, l) \
  __builtin_amdgcn_global_load_lds((const __attribute__((address_space(1))) void*)(g), \
                                   (__attribute__((address_space(3))) void*)(l), 16, 0, 0)

// ---------------- fp32 -> bf16 cast, 8 elems/thread ----------------
__global__ void cast_bf16_k(const float* __restrict__ in, ushortT* __restrict__ out, int n8) {
  int i = blockIdx.x * blockDim.x + threadIdx.x;
  if (i >= n8) return;
  const float4* p = (const float4*)in;
  float4 a = p[2 * i], b = p[2 * i + 1];
  uint4 o;
  o.x = (unsigned)f2bf(a.x) | ((unsigned)f2bf(a.y) << 16);
  o.y = (unsigned)f2bf(a.z) | ((unsigned)f2bf(a.w) << 16);
  o.z = (unsigned)f2bf(b.x) | ((unsigned)f2bf(b.y) << 16);
  o.w = (unsigned)f2bf(b.z) | ((unsigned)f2bf(b.w) << 16);
  ((uint4*)out)[i] = o;
}

// fused 4-weight cast (each weight 1M elements), dsts contiguous at out
__global__ void cast4_bf16_k(const float* __restrict__ a, const float* __restrict__ b,
                             const float* __restrict__ c, const float* __restrict__ d,
                             ushortT* __restrict__ out) {
  int idx = blockIdx.x * blockDim.x + threadIdx.x;   // 4 * 131072
  int w = idx >> 17, i = idx & 131071;
  const float* src = (w == 0) ? a : (w == 1) ? b : (w == 2) ? c : d;
  const float4* p = (const float4*)src;
  float4 x = p[2 * i], y = p[2 * i + 1];
  uint4 o;
  o.x = (unsigned)f2bf(x.x) | ((unsigned)f2bf(x.y) << 16);
  o.y = (unsigned)f2bf(x.z) | ((unsigned)f2bf(x.w) << 16);
  o.z = (unsigned)f2bf(y.x) | ((unsigned)f2bf(y.y) << 16);
  o.w = (unsigned)f2bf(y.z) | ((unsigned)f2bf(y.w) << 16);
  ((uint4*)(out + ((size_t)w << 20)))[i] = o;
}

// ---------------- log2(size) ----------------
__global__ void l2size_k(const float* __restrict__ sz, float* __restrict__ l2s, int n) {
  int i = blockIdx.x * blockDim.x + threadIdx.x;
  if (i < n) l2s[i] = __log2f(sz[i]);
}

// ---------------- GEMM: C[M,N] = A[M,K] @ B[N,K]^T + bias ----------------
struct GemmArgs { const ushortT* B; const float* bias; void* dst; int mode; };
// mode 0: Q -> bf16 [h][t][64] * 0.125   mode 1: K -> bf16 [h][t][64]
// mode 2: V -> bf16 [h][64][t] (transposed)      mode 3: fp32 [m][1024]

__global__ __launch_bounds__(256, 3) void gemm_bt_k(
    const ushortT* __restrict__ A, GemmArgs g0, GemmArgs g1, GemmArgs g2)
{
  constexpr int K = 1024;
  __shared__ __align__(16) ushortT As[128 * 64];
  __shared__ __align__(16) ushortT Bs[128 * 64];

  GemmArgs g = (blockIdx.y == 0) ? g0 : ((blockIdx.y == 1) ? g1 : g2);
  const ushortT* __restrict__ Bw = g.B;

  const int tid = threadIdx.x;
  const int wv = tid >> 6, ln = tid & 63;
  // XCD-locality decode (T1): nb = id&7 so each XCD serves ONE 128-col B-panel
  const int nb = blockIdx.x & 7, mb = blockIdx.x >> 3;      // 8 x 32 blocks
  const int m0 = mb * 128, n0 = nb * 128;
  const int wr = wv >> 1, wc = wv & 1;
  const int lrow = ln & 15, lq = ln >> 4;

  const int rstg = wv * 8 + (ln >> 3);
  const int ustg = (ln & 7) ^ (ln >> 3);

  f32x4 acc[4][4] = {};

  for (int kt = 0; kt < K; kt += 64) {
#pragma unroll
    for (int i = 0; i < 4; ++i) {
      int r = i * 32 + rstg;
      GLOAD_LDS16(A  + (size_t)(m0 + r) * K + kt + (ustg << 3), As + i * 2048 + wv * 512);
      GLOAD_LDS16(Bw + (size_t)(n0 + r) * K + kt + (ustg << 3), Bs + i * 2048 + wv * 512);
    }
    __syncthreads();
#pragma unroll
    for (int ks = 0; ks < 2; ++ks) {
      short8 a[4], b[4];
#pragma unroll
      for (int mi = 0; mi < 4; ++mi) {
        int ra = wr * 64 + mi * 16 + lrow;
        int u = (ks * 4 + lq) ^ (ra & 7);
        a[mi] = *(const short8*)(As + ra * 64 + (u << 3));
      }
#pragma unroll
      for (int ni = 0; ni < 4; ++ni) {
        int rb = wc * 64 + ni * 16 + lrow;
        int u = (ks * 4 + lq) ^ (rb & 7);
        b[ni] = *(const short8*)(Bs + rb * 64 + (u << 3));
      }
#pragma unroll
      for (int mi = 0; mi < 4; ++mi)
#pragma unroll
        for (int ni = 0; ni < 4; ++ni)
          acc[mi][ni] = __builtin_amdgcn_mfma_f32_16x16x32_bf16(a[mi], b[ni], acc[mi][ni], 0, 0, 0);
    }
    __syncthreads();
  }

  const int mode = g.mode;
  if (mode <= 1) {
    ushortT* dst = (ushortT*)g.dst;
    const float sc = (mode == 0) ? 0.125f : 1.0f;
#pragma unroll
    for (int ni = 0; ni < 4; ++ni) {
      int n = n0 + wc * 64 + ni * 16 + lrow;
      float bsv = g.bias[n];
      size_t base = ((size_t)(n >> 6) * L_SEQ) * HD + (n & 63);
#pragma unroll
      for (int mi = 0; mi < 4; ++mi)
#pragma unroll
        for (int r = 0; r < 4; ++r) {
          int m = m0 + wr * 64 + mi * 16 + lq * 4 + r;
          dst[base + (size_t)m * HD] = f2bf((acc[mi][ni][r] + bsv) * sc);
        }
    }
  } else if (mode == 2) {
    ushortT* dst = (ushortT*)g.dst;
#pragma unroll
    for (int ni = 0; ni < 4; ++ni) {
      int n = n0 + wc * 64 + ni * 16 + lrow;     // n == h*64+hd
      float bsv = g.bias[n];
      size_t base = (size_t)n * L_SEQ;
#pragma unroll
      for (int mi = 0; mi < 4; ++mi)
#pragma unroll
        for (int r = 0; r < 4; ++r) {
          int m = m0 + wr * 64 + mi * 16 + lq * 4 + r;
          dst[base + m] = f2bf(acc[mi][ni][r] + bsv);
        }
    }
  } else {
    float* dst = (float*)g.dst;
#pragma unroll
    for (int ni = 0; ni < 4; ++ni) {
      int n = n0 + wc * 64 + ni * 16 + lrow;
      float bsv = g.bias[n];
#pragma unroll
      for (int mi = 0; mi < 4; ++mi)
#pragma unroll
        for (int r = 0; r < 4; ++r) {
          int m = m0 + wr * 64 + mi * 16 + lq * 4 + r;
          dst[(size_t)m * EMBED + n] = acc[mi][ni][r] + bsv;
        }
    }
  }
}

// ---------------- flash attention (swapped-operand 16x16, lane-owns-q-row) ----
// 1024 blocks, XCD head-clustering swizzle. Per wave: 16 q-rows, lane owns
// q = lane&15 entirely. S^T = mfma(K_frag, Q_frag) (operand swap; A/B frag
// layouts are identical lane->(dim16,k) maps, so the SAME register contents
// serve swapped roles). Lane then holds S^T[key=16f+4lq+r][q=lrow]:
//  - softmax: in-lane tree + 2 shfl_xor (16/32) -- no DPP chains, no P LDS
//  - P packs in-register (8 cvt_pk) feeding PV's B operand directly
//  - PV: O^T = mfma(V_frag, P_frag) with key-permutation kappa(lq,j) =
//    {4lq+j, 16+4lq+j-4} applied to BOTH operands (k-order is internal);
//    V read as 16 ds_read_b64 from the swizzled Vs (slot ^= lrow&7).
// Ps buffer deleted: LDS 25600 -> 16384 B. Epilogue: 4 x 8B packed stores.
__global__ __launch_bounds__(256, 4) void attn_k(
    const ushortT* __restrict__ Q,   // [16][4096][64], pre-scaled by 0.125
    const ushortT* __restrict__ Kb,  // [16][4096][64]
    const ushortT* __restrict__ Vt,  // [16][64][4096]
    const float*   __restrict__ l2s, // [4096] log2(size)
    ushortT* __restrict__ O)         // [4096][1024] bf16
{
  __shared__ __align__(16) ushortT Ks[64 * 64];
  __shared__ __align__(16) ushortT Vs[64 * 64];

  const int id = blockIdx.x;                 // 0..1023
  const int xcd = id & 7, s = id >> 3;
  const int h  = xcd * 2 + (s >> 6);         // head (2 per XCD)
  const int q0 = (s & 63) * 64;              // q-tile base

  const int tid = threadIdx.x;
  const int wv = tid >> 6, ln = tid & 63;
  const int lrow = ln & 15, lq = ln >> 4;

  short8 qf0, qf1;  // Q fragments (16-dim = q on lane&15, k = lq*8+j)
  {
    const ushortT* qp = Q + ((size_t)h * L_SEQ + q0 + wv * 16 + lrow) * HD + lq * 8;
    qf0 = *(const short8*)qp;
    qf1 = *(const short8*)(qp + 32);
  }

  f32x4 o[4] = {};                  // O^T: o[df][r] = O[d=16df+4lq+r][q=lrow]
  float mrun = -1e30f, lrun = 0.f;  // lane-local (lane's q row)

  const int rstg = wv * 8 + (ln >> 3);
  const int ustg = (ln & 7) ^ (ln >> 3);

  // loop-invariant V-read byte offsets (key groups {4lq,16+4lq,32+4lq,48+4lq},
  // slot = natural ^ (lrow&7); d = 16df+lrow so d&7 == lrow&7, df-invariant)
  const int sw = lrow & 7;
  const int vo0 = lrow * 128 + ((((lq >> 1))     ^ sw) << 4) + (lq & 1) * 8;
  const int vo1 = lrow * 128 + ((((lq >> 1) + 2) ^ sw) << 4) + (lq & 1) * 8;
  const int vo2 = lrow * 128 + ((((lq >> 1) + 4) ^ sw) << 4) + (lq & 1) * 8;
  const int vo3 = lrow * 128 + ((((lq >> 1) + 6) ^ sw) << 4) + (lq & 1) * 8;
  const char* Vb = (const char*)Vs;

  for (int t = 0; t < L_SEQ / 64; ++t) {
    const int t0 = t * 64;
#pragma unroll
    for (int i = 0; i < 2; ++i) {
      int r = i * 32 + rstg;
      GLOAD_LDS16(Kb + ((size_t)h * L_SEQ + t0 + r) * HD + (ustg << 3), Ks + i * 2048 + wv * 512);
      GLOAD_LDS16(Vt + ((size_t)(h * HD + r)) * L_SEQ + t0 + (ustg << 3), Vs + i * 2048 + wv * 512);
    }
    __syncthreads();

    // S^T = K Q (swapped operands): lane gets key=16f+4lq+r rows, q=lrow col
    f32x4 sfr[4] = {};
    __builtin_amdgcn_s_setprio(1);
#pragma unroll
    for (int ks = 0; ks < 2; ++ks) {
      short8 qa = ks ? qf1 : qf0;
#pragma unroll
      for (int f = 0; f < 4; ++f) {
        int key = f * 16 + lrow;
        int u = (ks * 4 + lq) ^ (key & 7);
        short8 kb = *(const short8*)(Ks + key * 64 + (u << 3));
        sfr[f] = __builtin_amdgcn_mfma_f32_16x16x32_bf16(kb, qa, sfr[f], 0, 0, 0);
      }
    }
    __builtin_amdgcn_s_setprio(0);

    // base-2 logits + log2(size_key); key of sfr[f][r] = 16f + 4lq + r
#pragma unroll
    for (int f = 0; f < 4; ++f) {
      f32x4 b = *(const f32x4*)(l2s + t0 + f * 16 + lq * 4);
#pragma unroll
      for (int r = 0; r < 4; ++r)
        sfr[f][r] = sfr[f][r] * LOG2E + b[r];
    }

    // softmax (lane owns its whole q row): in-lane tree + 2 cross-lane steps
    float pm = fmaxf(fmaxf(fmaxf(sfr[0][0], sfr[0][1]), fmaxf(sfr[0][2], sfr[0][3])),
                     fmaxf(fmaxf(sfr[1][0], sfr[1][1]), fmaxf(sfr[1][2], sfr[1][3])));
    pm = fmaxf(pm, fmaxf(fmaxf(fmaxf(sfr[2][0], sfr[2][1]), fmaxf(sfr[2][2], sfr[2][3])),
                         fmaxf(fmaxf(sfr[3][0], sfr[3][1]), fmaxf(sfr[3][2], sfr[3][3]))));
    pm = fmaxf(pm, __shfl_xor(pm, 16));
    pm = fmaxf(pm, __shfl_xor(pm, 32));
    float mnew  = fmaxf(mrun, pm);
    float alpha = __builtin_amdgcn_exp2f(mrun - mnew);
    mrun = mnew;

    float rs = 0.f;
#pragma unroll
    for (int f = 0; f < 4; ++f)
#pragma unroll
      for (int r = 0; r < 4; ++r) {
        float pv = __builtin_amdgcn_exp2f(sfr[f][r] - mrun);
        sfr[f][r] = pv;
        rs += pv;
      }
    rs += __shfl_xor(rs, 16);
    rs += __shfl_xor(rs, 32);
    lrun = lrun * alpha + rs;

    if (!__all(alpha == 1.0f)) {     // skip O-rescale when no max growth
#pragma unroll
      for (int df = 0; df < 4; ++df)
#pragma unroll
        for (int r = 0; r < 4; ++r) o[df][r] *= alpha;
    }

    // P -> bf16 B-fragments in-register; slot j of lane-group lq holds key
    // kappa(lq,j) = j<4 ? (f_lo*16 + 4lq + j) : (f_hi*16 + 4lq + j-4)
    short8 pb0, pb1;
    {
      unsigned p0 = cvtpk(sfr[0][0], sfr[0][1]), p1 = cvtpk(sfr[0][2], sfr[0][3]);
      unsigned p2 = cvtpk(sfr[1][0], sfr[1][1]), p3 = cvtpk(sfr[1][2], sfr[1][3]);
      unsigned p4 = cvtpk(sfr[2][0], sfr[2][1]), p5 = cvtpk(sfr[2][2], sfr[2][3]);
      unsigned p6 = cvtpk(sfr[3][0], sfr[3][1]), p7 = cvtpk(sfr[3][2], sfr[3][3]);
      pb0 = __builtin_bit_cast(short8, (uint4v){p0, p1, p2, p3});  // keys 0..31
      pb1 = __builtin_bit_cast(short8, (uint4v){p4, p5, p6, p7});  // keys 32..63
    }

    // O^T += V P : A-frag = V^T rows d=16df+lrow with the SAME kappa ordering
    __builtin_amdgcn_s_setprio(1);
#pragma unroll
    for (int df = 0; df < 4; ++df) {
      const char* vr = Vb + df * 2048;
      uint2 a0 = *(const uint2*)(vr + vo0);
      uint2 a1 = *(const uint2*)(vr + vo1);
      short8 va = __builtin_bit_cast(short8, (uint4v){a0.x, a0.y, a1.x, a1.y});
      o[df] = __builtin_amdgcn_mfma_f32_16x16x32_bf16(va, pb0, o[df], 0, 0, 0);
      uint2 a2 = *(const uint2*)(vr + vo2);
      uint2 a3 = *(const uint2*)(vr + vo3);
      short8 vb2 = __builtin_bit_cast(short8, (uint4v){a2.x, a2.y, a3.x, a3.y});
      o[df] = __builtin_amdgcn_mfma_f32_16x16x32_bf16(vb2, pb1, o[df], 0, 0, 0);
    }
    __builtin_amdgcn_s_setprio(0);

    __syncthreads();
  }

  // epilogue: O[q][h*64+d] = o^T / lrun; 4 packed 8B stores
  float inv = 1.0f / lrun;
  ushortT* ob = O + (size_t)(q0 + wv * 16 + lrow) * EMBED + h * HD;
#pragma unroll
  for (int df = 0; df < 4; ++df) {
    uint2 w;
    w.x = (unsigned)f2bf(o[df][0] * inv) | ((unsigned)f2bf(o[df][1] * inv) << 16);
    w.y = (unsigned)f2bf(o[df][2] * inv) | ((unsigned)f2bf(o[df][3] * inv) << 16);
    *(uint2*)(ob + df * 16 + lq * 4) = w;
  }
}

// ---------------- metric = mean over heads of K ----------------
__global__ void metric_k(const ushortT* __restrict__ Kb, float* __restrict__ out) {
  int idx = blockIdx.x * blockDim.x + threadIdx.x;   // t*8 + c8
  int t = idx >> 3, c8 = idx & 7;
  float acc[8] = {};
#pragma unroll
  for (int h = 0; h < HEADS; ++h) {
    short8 v = *(const short8*)(Kb + ((size_t)h * L_SEQ + t) * HD + c8 * 8);
#pragma unroll
    for (int j = 0; j < 8; ++j) acc[j] += bf2f((ushortT)v[j]);
  }
  float* dst = out + (size_t)t * HD + c8 * 8;
#pragma unroll
  for (int j = 0; j < 8; ++j) dst[j] = acc[j] * (1.0f / 16.0f);
}

extern "C" void kernel_launch(void* const* d_in, const int* in_sizes, int n_in,
                              void* d_out, int out_size, void* d_ws, size_t ws_size,
                              hipStream_t stream) {
  const float* hs = (const float*)d_in[0];
  const float* sz = (const float*)d_in[1];
  const float* wq = (const float*)d_in[2];
  const float* bq = (const float*)d_in[3];
  const float* wk = (const float*)d_in[4];
  const float* bk = (const float*)d_in[5];
  const float* wv = (const float*)d_in[6];
  const float* bv = (const float*)d_in[7];
  const float* wo = (const float*)d_in[8];
  const float* bo = (const float*)d_in[9];

  char* ws = (char*)d_ws;
  ushortT* hs_b = (ushortT*)(ws);                 // [4096][1024] bf16
  ushortT* wq_b = (ushortT*)(ws + (8u << 20));    // 4 weights bf16 (contiguous)
  ushortT* wk_b = wq_b + (1u << 20);
  ushortT* wv_b = wq_b + (2u << 20);
  ushortT* wo_b = wq_b + (3u << 20);
  ushortT* q_b  = (ushortT*)(ws + (16u << 20));   // [16][4096][64]
  ushortT* k_b  = (ushortT*)(ws + (24u << 20));   // [16][4096][64]
  ushortT* vt_b = (ushortT*)(ws + (32u << 20));   // [16][64][4096]
  ushortT* at_b = (ushortT*)(ws + (40u << 20));   // [4096][1024]
  float*   l2s  = (float*)(ws + (48u << 20));     // [4096]

  float* outp    = (float*)d_out;
  float* metricp = outp + (size_t)L_SEQ * EMBED;

  cast_bf16_k<<<L_SEQ * EMBED / 8 / 256, 256, 0, stream>>>(hs, hs_b, L_SEQ * EMBED / 8);
  cast4_bf16_k<<<2048, 256, 0, stream>>>(wq, wk, wv, wo, wq_b);
  l2size_k<<<L_SEQ / 256, 256, 0, stream>>>(sz, l2s, L_SEQ);

  GemmArgs aq{wq_b, bq, (void*)q_b, 0};
  GemmArgs ak{wk_b, bk, (void*)k_b, 1};
  GemmArgs av{wv_b, bv, (void*)vt_b, 2};
  gemm_bt_k<<<dim3(256, 3), 256, 0, stream>>>(hs_b, aq, ak, av);   // fused QKV

  metric_k<<<L_SEQ * 8 / 256, 256, 0, stream>>>(k_b, metricp);

  attn_k<<<1024, 256, 0, stream>>>(q_b, k_b, vt_b, l2s, at_b);

  GemmArgs ao{wo_b, bo, (void*)outp, 3};
  gemm_bt_k<<<dim3(256, 1), 256, 0, stream>>>(at_b, ao, ao, ao);   // O projection
}

// Round 16
// 215.147 us; speedup vs baseline: 1.8065x; 1.0071x over previous
//
#include <hip/hip_runtime.h>

// Problem: B=1, L=4096, EMBED=1024, 16 heads x 64
static constexpr int L_SEQ = 4096;
static constexpr int EMBED = 1024;
static constexpr int HEADS = 16;
static constexpr int HD    = 64;

typedef unsigned short ushortT;
typedef __attribute__((ext_vector_type(8)))  short short8;   // 8 x bf16 (4 VGPR)
typedef __attribute__((ext_vector_type(4)))  float f32x4;
typedef __attribute__((ext_vector_type(4)))  unsigned uint4v;

#define LOG2E 1.4426950408889634f

__device__ __forceinline__ ushortT f2bf(float f) {
  unsigned u = __builtin_bit_cast(unsigned, f);
  u += 0x7fffu + ((u >> 16) & 1u);          // round-to-nearest-even
  return (ushortT)(u >> 16);
}
__device__ __forceinline__ float bf2f(ushortT s) {
  return __builtin_bit_cast(float, ((unsigned)s) << 16);
}
// v_cvt_pk_bf16_f32: two f32 -> u32 of 2x bf16 (lo=a, hi=b), RNE on CDNA4
__device__ __forceinline__ unsigned cvtpk(float a, float b) {
  unsigned r;
  asm("v_cvt_pk_bf16_f32 %0, %1, %2" : "=v"(r) : "v"(a), "v"(b));
  return r;
}

// async global->LDS, 16B/lane; LDS dest is wave-uniform base + lane*16.
#define GLOAD_LDS16(g, l) \
  __builtin_amdgcn_global_load_lds((const __attribute__((address_space(1))) void*)(g), \
                                   (__attribute__((address_space(3))) void*)(l), 16, 0, 0)

// ---------------- fp32 -> bf16 cast, 8 elems/thread ----------------
__global__ void cast_bf16_k(const float* __restrict__ in, ushortT* __restrict__ out, int n8) {
  int i = blockIdx.x * blockDim.x + threadIdx.x;
  if (i >= n8) return;
  const float4* p = (const float4*)in;
  float4 a = p[2 * i], b = p[2 * i + 1];
  uint4 o;
  o.x = (unsigned)f2bf(a.x) | ((unsigned)f2bf(a.y) << 16);
  o.y = (unsigned)f2bf(a.z) | ((unsigned)f2bf(a.w) << 16);
  o.z = (unsigned)f2bf(b.x) | ((unsigned)f2bf(b.y) << 16);
  o.w = (unsigned)f2bf(b.z) | ((unsigned)f2bf(b.w) << 16);
  ((uint4*)out)[i] = o;
}

// fused 4-weight cast (each weight 1M elements), dsts contiguous at out
__global__ void cast4_bf16_k(const float* __restrict__ a, const float* __restrict__ b,
                             const float* __restrict__ c, const float* __restrict__ d,
                             ushortT* __restrict__ out) {
  int idx = blockIdx.x * blockDim.x + threadIdx.x;   // 4 * 131072
  int w = idx >> 17, i = idx & 131071;
  const float* src = (w == 0) ? a : (w == 1) ? b : (w == 2) ? c : d;
  const float4* p = (const float4*)src;
  float4 x = p[2 * i], y = p[2 * i + 1];
  uint4 o;
  o.x = (unsigned)f2bf(x.x) | ((unsigned)f2bf(x.y) << 16);
  o.y = (unsigned)f2bf(x.z) | ((unsigned)f2bf(x.w) << 16);
  o.z = (unsigned)f2bf(y.x) | ((unsigned)f2bf(y.y) << 16);
  o.w = (unsigned)f2bf(y.z) | ((unsigned)f2bf(y.w) << 16);
  ((uint4*)(out + ((size_t)w << 20)))[i] = o;
}

// ---------------- log2(size) ----------------
__global__ void l2size_k(const float* __restrict__ sz, float* __restrict__ l2s, int n) {
  int i = blockIdx.x * blockDim.x + threadIdx.x;
  if (i < n) l2s[i] = __log2f(sz[i]);
}

// ---------------- GEMM: C[M,N] = A[M,K] @ B[N,K]^T + bias ----------------
struct GemmArgs { const ushortT* B; const float* bias; void* dst; int mode; };
// mode 0: Q -> bf16 [h][t][64] * 0.125   mode 1: K -> bf16 [h][t][64]
// mode 2: V -> bf16 [h][64][t] (transposed)      mode 3: fp32 [m][1024]

__global__ __launch_bounds__(256, 3) void gemm_bt_k(
    const ushortT* __restrict__ A, GemmArgs g0, GemmArgs g1, GemmArgs g2)
{
  constexpr int K = 1024;
  __shared__ __align__(16) ushortT As[128 * 64];
  __shared__ __align__(16) ushortT Bs[128 * 64];

  GemmArgs g = (blockIdx.y == 0) ? g0 : ((blockIdx.y == 1) ? g1 : g2);
  const ushortT* __restrict__ Bw = g.B;

  const int tid = threadIdx.x;
  const int wv = tid >> 6, ln = tid & 63;
  // XCD-locality decode (T1): nb = id&7 so each XCD serves ONE 128-col B-panel
  const int nb = blockIdx.x & 7, mb = blockIdx.x >> 3;      // 8 x 32 blocks
  const int m0 = mb * 128, n0 = nb * 128;
  const int wr = wv >> 1, wc = wv & 1;
  const int lrow = ln & 15, lq = ln >> 4;

  const int rstg = wv * 8 + (ln >> 3);
  const int ustg = (ln & 7) ^ (ln >> 3);

  f32x4 acc[4][4] = {};

  for (int kt = 0; kt < K; kt += 64) {
#pragma unroll
    for (int i = 0; i < 4; ++i) {
      int r = i * 32 + rstg;
      GLOAD_LDS16(A  + (size_t)(m0 + r) * K + kt + (ustg << 3), As + i * 2048 + wv * 512);
      GLOAD_LDS16(Bw + (size_t)(n0 + r) * K + kt + (ustg << 3), Bs + i * 2048 + wv * 512);
    }
    __syncthreads();
#pragma unroll
    for (int ks = 0; ks < 2; ++ks) {
      short8 a[4], b[4];
#pragma unroll
      for (int mi = 0; mi < 4; ++mi) {
        int ra = wr * 64 + mi * 16 + lrow;
        int u = (ks * 4 + lq) ^ (ra & 7);
        a[mi] = *(const short8*)(As + ra * 64 + (u << 3));
      }
#pragma unroll
      for (int ni = 0; ni < 4; ++ni) {
        int rb = wc * 64 + ni * 16 + lrow;
        int u = (ks * 4 + lq) ^ (rb & 7);
        b[ni] = *(const short8*)(Bs + rb * 64 + (u << 3));
      }
#pragma unroll
      for (int mi = 0; mi < 4; ++mi)
#pragma unroll
        for (int ni = 0; ni < 4; ++ni)
          acc[mi][ni] = __builtin_amdgcn_mfma_f32_16x16x32_bf16(a[mi], b[ni], acc[mi][ni], 0, 0, 0);
    }
    __syncthreads();
  }

  const int mode = g.mode;
  if (mode <= 1) {
    ushortT* dst = (ushortT*)g.dst;
    const float sc = (mode == 0) ? 0.125f : 1.0f;
#pragma unroll
    for (int ni = 0; ni < 4; ++ni) {
      int n = n0 + wc * 64 + ni * 16 + lrow;
      float bsv = g.bias[n];
      size_t base = ((size_t)(n >> 6) * L_SEQ) * HD + (n & 63);
#pragma unroll
      for (int mi = 0; mi < 4; ++mi)
#pragma unroll
        for (int r = 0; r < 4; ++r) {
          int m = m0 + wr * 64 + mi * 16 + lq * 4 + r;
          dst[base + (size_t)m * HD] = f2bf((acc[mi][ni][r] + bsv) * sc);
        }
    }
  } else if (mode == 2) {
    ushortT* dst = (ushortT*)g.dst;
#pragma unroll
    for (int ni = 0; ni < 4; ++ni) {
      int n = n0 + wc * 64 + ni * 16 + lrow;     // n == h*64+hd
      float bsv = g.bias[n];
      size_t base = (size_t)n * L_SEQ;
#pragma unroll
      for (int mi = 0; mi < 4; ++mi)
#pragma unroll
        for (int r = 0; r < 4; ++r) {
          int m = m0 + wr * 64 + mi * 16 + lq * 4 + r;
          dst[base + m] = f2bf(acc[mi][ni][r] + bsv);
        }
    }
  } else {
    float* dst = (float*)g.dst;
#pragma unroll
    for (int ni = 0; ni < 4; ++ni) {
      int n = n0 + wc * 64 + ni * 16 + lrow;
      float bsv = g.bias[n];
#pragma unroll
      for (int mi = 0; mi < 4; ++mi)
#pragma unroll
        for (int r = 0; r < 4; ++r) {
          int m = m0 + wr * 64 + mi * 16 + lq * 4 + r;
          dst[(size_t)m * EMBED + n] = acc[mi][ni][r] + bsv;
        }
    }
  }
}

// ---------------- flash attention (swapped-operand 16x16 + K/V dbuf) ---------
// R15 structure (lane owns q-row, in-register P, no P LDS) + R16: K/V double-
// buffered (stage t+1 issued BEFORE compute t, ONE barrier/tile — by barrier
// time the loads have ~2500 issue-cycles of compute behind them, so the
// pre-barrier vmcnt(0) drain waits ~0) and strength-reduced staging addresses
// (per-lane base pointers + 32-bit tile offsets, no per-tile 64-bit muls).
// LDS 2*(8K+8K) = 32768 B -> 5 blocks/CU capacity, grid-capped 4 (unchanged).
__global__ __launch_bounds__(256, 4) void attn_k(
    const ushortT* __restrict__ Q,   // [16][4096][64], pre-scaled by 0.125
    const ushortT* __restrict__ Kb,  // [16][4096][64]
    const ushortT* __restrict__ Vt,  // [16][64][4096]
    const float*   __restrict__ l2s, // [4096] log2(size)
    ushortT* __restrict__ O)         // [4096][1024] bf16
{
  __shared__ __align__(16) ushortT Ks[2][64 * 64];
  __shared__ __align__(16) ushortT Vs[2][64 * 64];

  const int id = blockIdx.x;                 // 0..1023
  const int xcd = id & 7, s = id >> 3;
  const int h  = xcd * 2 + (s >> 6);         // head (2 per XCD)
  const int q0 = (s & 63) * 64;              // q-tile base

  const int tid = threadIdx.x;
  const int wv = tid >> 6, ln = tid & 63;
  const int lrow = ln & 15, lq = ln >> 4;

  short8 qf0, qf1;  // Q fragments (16-dim = q on lane&15, k = lq*8+j)
  {
    const ushortT* qp = Q + ((size_t)h * L_SEQ + q0 + wv * 16 + lrow) * HD + lq * 8;
    qf0 = *(const short8*)qp;
    qf1 = *(const short8*)(qp + 32);
  }

  f32x4 o[4] = {};                  // O^T: o[df][r] = O[d=16df+4lq+r][q=lrow]
  float mrun = -1e30f, lrun = 0.f;  // lane-local (lane's q row)

  const int rstg = wv * 8 + (ln >> 3);
  const int ustg = (ln & 7) ^ (ln >> 3);

  // strength-reduced staging bases (64-bit math once; 32-bit offsets per tile)
  const ushortT* kbase = Kb + ((size_t)h * L_SEQ + rstg) * HD + (ustg << 3);
  const ushortT* vbase = Vt + ((size_t)(h * HD) + rstg) * L_SEQ + (ustg << 3);

  auto STAGE = [&](int buf, int t0) {
#pragma unroll
    for (int i = 0; i < 2; ++i) {
      GLOAD_LDS16(kbase + t0 * 64 + i * (32 * HD),    &Ks[buf][i * 2048 + wv * 512]);
      GLOAD_LDS16(vbase + t0 + i * (32 * L_SEQ),      &Vs[buf][i * 2048 + wv * 512]);
    }
  };

  // loop-invariant V-read byte offsets (key groups {4lq,16+4lq,32+4lq,48+4lq},
  // slot = natural ^ (lrow&7); d = 16df+lrow so d&7 == lrow&7, df-invariant)
  const int sw = lrow & 7;
  const int vo0 = lrow * 128 + ((((lq >> 1))     ^ sw) << 4) + (lq & 1) * 8;
  const int vo1 = lrow * 128 + ((((lq >> 1) + 2) ^ sw) << 4) + (lq & 1) * 8;
  const int vo2 = lrow * 128 + ((((lq >> 1) + 4) ^ sw) << 4) + (lq & 1) * 8;
  const int vo3 = lrow * 128 + ((((lq >> 1) + 6) ^ sw) << 4) + (lq & 1) * 8;

  STAGE(0, 0);
  __syncthreads();                   // tile 0 resident

  constexpr int NT = L_SEQ / 64;
#pragma unroll 1
  for (int t = 0; t < NT; ++t) {
    const int cur = t & 1;
    if (t + 1 < NT) STAGE(cur ^ 1, (t + 1) * 64);   // overlaps entire compute
    const int t0 = t * 64;
    const ushortT* Kt = &Ks[cur][0];
    const char*    Vb = (const char*)&Vs[cur][0];

    // S^T = K Q (swapped operands): lane gets key=16f+4lq+r rows, q=lrow col
    f32x4 sfr[4] = {};
    __builtin_amdgcn_s_setprio(1);
#pragma unroll
    for (int ks = 0; ks < 2; ++ks) {
      short8 qa = ks ? qf1 : qf0;
#pragma unroll
      for (int f = 0; f < 4; ++f) {
        int key = f * 16 + lrow;
        int u = (ks * 4 + lq) ^ (key & 7);
        short8 kb = *(const short8*)(Kt + key * 64 + (u << 3));
        sfr[f] = __builtin_amdgcn_mfma_f32_16x16x32_bf16(kb, qa, sfr[f], 0, 0, 0);
      }
    }
    __builtin_amdgcn_s_setprio(0);

    // base-2 logits + log2(size_key); key of sfr[f][r] = 16f + 4lq + r
#pragma unroll
    for (int f = 0; f < 4; ++f) {
      f32x4 b = *(const f32x4*)(l2s + t0 + f * 16 + lq * 4);
#pragma unroll
      for (int r = 0; r < 4; ++r)
        sfr[f][r] = sfr[f][r] * LOG2E + b[r];
    }

    // softmax (lane owns its whole q row): in-lane tree + 2 cross-lane steps
    float pm = fmaxf(fmaxf(fmaxf(sfr[0][0], sfr[0][1]), fmaxf(sfr[0][2], sfr[0][3])),
                     fmaxf(fmaxf(sfr[1][0], sfr[1][1]), fmaxf(sfr[1][2], sfr[1][3])));
    pm = fmaxf(pm, fmaxf(fmaxf(fmaxf(sfr[2][0], sfr[2][1]), fmaxf(sfr[2][2], sfr[2][3])),
                         fmaxf(fmaxf(sfr[3][0], sfr[3][1]), fmaxf(sfr[3][2], sfr[3][3]))));
    pm = fmaxf(pm, __shfl_xor(pm, 16));
    pm = fmaxf(pm, __shfl_xor(pm, 32));
    float mnew  = fmaxf(mrun, pm);
    float alpha = __builtin_amdgcn_exp2f(mrun - mnew);
    mrun = mnew;

    float rs = 0.f;
#pragma unroll
    for (int f = 0; f < 4; ++f)
#pragma unroll
      for (int r = 0; r < 4; ++r) {
        float pv = __builtin_amdgcn_exp2f(sfr[f][r] - mrun);
        sfr[f][r] = pv;
        rs += pv;
      }
    rs += __shfl_xor(rs, 16);
    rs += __shfl_xor(rs, 32);
    lrun = lrun * alpha + rs;

    if (!__all(alpha == 1.0f)) {     // skip O-rescale when no max growth
#pragma unroll
      for (int df = 0; df < 4; ++df)
#pragma unroll
        for (int r = 0; r < 4; ++r) o[df][r] *= alpha;
    }

    // P -> bf16 B-fragments in-register; slot j of lane-group lq holds key
    // kappa(lq,j) = j<4 ? (f_lo*16 + 4lq + j) : (f_hi*16 + 4lq + j-4)
    short8 pb0, pb1;
    {
      unsigned p0 = cvtpk(sfr[0][0], sfr[0][1]), p1 = cvtpk(sfr[0][2], sfr[0][3]);
      unsigned p2 = cvtpk(sfr[1][0], sfr[1][1]), p3 = cvtpk(sfr[1][2], sfr[1][3]);
      unsigned p4 = cvtpk(sfr[2][0], sfr[2][1]), p5 = cvtpk(sfr[2][2], sfr[2][3]);
      unsigned p6 = cvtpk(sfr[3][0], sfr[3][1]), p7 = cvtpk(sfr[3][2], sfr[3][3]);
      pb0 = __builtin_bit_cast(short8, (uint4v){p0, p1, p2, p3});  // keys 0..31
      pb1 = __builtin_bit_cast(short8, (uint4v){p4, p5, p6, p7});  // keys 32..63
    }

    // O^T += V P : A-frag = V^T rows d=16df+lrow with the SAME kappa ordering
    __builtin_amdgcn_s_setprio(1);
#pragma unroll
    for (int df = 0; df < 4; ++df) {
      const char* vr = Vb + df * 2048;
      uint2 a0 = *(const uint2*)(vr + vo0);
      uint2 a1 = *(const uint2*)(vr + vo1);
      short8 va = __builtin_bit_cast(short8, (uint4v){a0.x, a0.y, a1.x, a1.y});
      o[df] = __builtin_amdgcn_mfma_f32_16x16x32_bf16(va, pb0, o[df], 0, 0, 0);
      uint2 a2 = *(const uint2*)(vr + vo2);
      uint2 a3 = *(const uint2*)(vr + vo3);
      short8 vb2 = __builtin_bit_cast(short8, (uint4v){a2.x, a2.y, a3.x, a3.y});
      o[df] = __builtin_amdgcn_mfma_f32_16x16x32_bf16(vb2, pb1, o[df], 0, 0, 0);
    }
    __builtin_amdgcn_s_setprio(0);

    __syncthreads();                 // drains next-tile loads; frees cur buffer
  }

  // epilogue: O[q][h*64+d] = o^T / lrun; 4 packed 8B stores
  float inv = 1.0f / lrun;
  ushortT* ob = O + (size_t)(q0 + wv * 16 + lrow) * EMBED + h * HD;
#pragma unroll
  for (int df = 0; df < 4; ++df) {
    uint2 w;
    w.x = (unsigned)f2bf(o[df][0] * inv) | ((unsigned)f2bf(o[df][1] * inv) << 16);
    w.y = (unsigned)f2bf(o[df][2] * inv) | ((unsigned)f2bf(o[df][3] * inv) << 16);
    *(uint2*)(ob + df * 16 + lq * 4) = w;
  }
}

// ---------------- metric = mean over heads of K ----------------
__global__ void metric_k(const ushortT* __restrict__ Kb, float* __restrict__ out) {
  int idx = blockIdx.x * blockDim.x + threadIdx.x;   // t*8 + c8
  int t = idx >> 3, c8 = idx & 7;
  float acc[8] = {};
#pragma unroll
  for (int h = 0; h < HEADS; ++h) {
    short8 v = *(const short8*)(Kb + ((size_t)h * L_SEQ + t) * HD + c8 * 8);
#pragma unroll
    for (int j = 0; j < 8; ++j) acc[j] += bf2f((ushortT)v[j]);
  }
  float* dst = out + (size_t)t * HD + c8 * 8;
#pragma unroll
  for (int j = 0; j < 8; ++j) dst[j] = acc[j] * (1.0f / 16.0f);
}

extern "C" void kernel_launch(void* const* d_in, const int* in_sizes, int n_in,
                              void* d_out, int out_size, void* d_ws, size_t ws_size,
                              hipStream_t stream) {
  const float* hs = (const float*)d_in[0];
  const float* sz = (const float*)d_in[1];
  const float* wq = (const float*)d_in[2];
  const float* bq = (const float*)d_in[3];
  const float* wk = (const float*)d_in[4];
  const float* bk = (const float*)d_in[5];
  const float* wv = (const float*)d_in[6];
  const float* bv = (const float*)d_in[7];
  const float* wo = (const float*)d_in[8];
  const float* bo = (const float*)d_in[9];

  char* ws = (char*)d_ws;
  ushortT* hs_b = (ushortT*)(ws);                 // [4096][1024] bf16
  ushortT* wq_b = (ushortT*)(ws + (8u << 20));    // 4 weights bf16 (contiguous)
  ushortT* wk_b = wq_b + (1u << 20);
  ushortT* wv_b = wq_b + (2u << 20);
  ushortT* wo_b = wq_b + (3u << 20);
  ushortT* q_b  = (ushortT*)(ws + (16u << 20));   // [16][4096][64]
  ushortT* k_b  = (ushortT*)(ws + (24u << 20));   // [16][4096][64]
  ushortT* vt_b = (ushortT*)(ws + (32u << 20));   // [16][64][4096]
  ushortT* at_b = (ushortT*)(ws + (40u << 20));   // [4096][1024]
  float*   l2s  = (float*)(ws + (48u << 20));     // [4096]

  float* outp    = (float*)d_out;
  float* metricp = outp + (size_t)L_SEQ * EMBED;

  cast_bf16_k<<<L_SEQ * EMBED / 8 / 256, 256, 0, stream>>>(hs, hs_b, L_SEQ * EMBED / 8);
  cast4_bf16_k<<<2048, 256, 0, stream>>>(wq, wk, wv, wo, wq_b);
  l2size_k<<<L_SEQ / 256, 256, 0, stream>>>(sz, l2s, L_SEQ);

  GemmArgs aq{wq_b, bq, (void*)q_b, 0};
  GemmArgs ak{wk_b, bk, (void*)k_b, 1};
  GemmArgs av{wv_b, bv, (void*)vt_b, 2};
  gemm_bt_k<<<dim3(256, 3), 256, 0, stream>>>(hs_b, aq, ak, av);   // fused QKV

  metric_k<<<L_SEQ * 8 / 256, 256, 0, stream>>>(k_b, metricp);

  attn_k<<<1024, 256, 0, stream>>>(q_b, k_b, vt_b, l2s, at_b);

  GemmArgs ao{wo_b, bo, (void*)outp, 3};
  gemm_bt_k<<<dim3(256, 1), 256, 0, stream>>>(at_b, ao, ao, ao);   // O projection
}

// Round 17
// 200.989 us; speedup vs baseline: 1.9338x; 1.0704x over previous
//
#include <hip/hip_runtime.h>

// Problem: B=1, L=4096, EMBED=1024, 16 heads x 64
static constexpr int L_SEQ = 4096;
static constexpr int EMBED = 1024;
static constexpr int HEADS = 16;
static constexpr int HD    = 64;

typedef unsigned short ushortT;
typedef __attribute__((ext_vector_type(8)))  short short8;   // 8 x bf16 (4 VGPR)
typedef __attribute__((ext_vector_type(4)))  float f32x4;
typedef __attribute__((ext_vector_type(4)))  unsigned uint4v;

#define LOG2E 1.4426950408889634f

__device__ __forceinline__ ushortT f2bf(float f) {
  unsigned u = __builtin_bit_cast(unsigned, f);
  u += 0x7fffu + ((u >> 16) & 1u);          // round-to-nearest-even
  return (ushortT)(u >> 16);
}
__device__ __forceinline__ float bf2f(ushortT s) {
  return __builtin_bit_cast(float, ((unsigned)s) << 16);
}
// v_cvt_pk_bf16_f32: two f32 -> u32 of 2x bf16 (lo=a, hi=b), RNE on CDNA4
__device__ __forceinline__ unsigned cvtpk(float a, float b) {
  unsigned r;
  asm("v_cvt_pk_bf16_f32 %0, %1, %2" : "=v"(r) : "v"(a), "v"(b));
  return r;
}

// async global->LDS, 16B/lane; LDS dest is wave-uniform base + lane*16.
#define GLOAD_LDS16(g, l) \
  __builtin_amdgcn_global_load_lds((const __attribute__((address_space(1))) void*)(g), \
                                   (__attribute__((address_space(3))) void*)(l), 16, 0, 0)

// ---------------- fp32 -> bf16 cast, 8 elems/thread ----------------
__global__ void cast_bf16_k(const float* __restrict__ in, ushortT* __restrict__ out, int n8) {
  int i = blockIdx.x * blockDim.x + threadIdx.x;
  if (i >= n8) return;
  const float4* p = (const float4*)in;
  float4 a = p[2 * i], b = p[2 * i + 1];
  uint4 o;
  o.x = (unsigned)f2bf(a.x) | ((unsigned)f2bf(a.y) << 16);
  o.y = (unsigned)f2bf(a.z) | ((unsigned)f2bf(a.w) << 16);
  o.z = (unsigned)f2bf(b.x) | ((unsigned)f2bf(b.y) << 16);
  o.w = (unsigned)f2bf(b.z) | ((unsigned)f2bf(b.w) << 16);
  ((uint4*)out)[i] = o;
}

// fused 4-weight cast (each weight 1M elements), dsts contiguous at out
__global__ void cast4_bf16_k(const float* __restrict__ a, const float* __restrict__ b,
                             const float* __restrict__ c, const float* __restrict__ d,
                             ushortT* __restrict__ out) {
  int idx = blockIdx.x * blockDim.x + threadIdx.x;   // 4 * 131072
  int w = idx >> 17, i = idx & 131071;
  const float* src = (w == 0) ? a : (w == 1) ? b : (w == 2) ? c : d;
  const float4* p = (const float4*)src;
  float4 x = p[2 * i], y = p[2 * i + 1];
  uint4 o;
  o.x = (unsigned)f2bf(x.x) | ((unsigned)f2bf(x.y) << 16);
  o.y = (unsigned)f2bf(x.z) | ((unsigned)f2bf(x.w) << 16);
  o.z = (unsigned)f2bf(y.x) | ((unsigned)f2bf(y.y) << 16);
  o.w = (unsigned)f2bf(y.z) | ((unsigned)f2bf(y.w) << 16);
  ((uint4*)(out + ((size_t)w << 20)))[i] = o;
}

// ---------------- log2(size) ----------------
__global__ void l2size_k(const float* __restrict__ sz, float* __restrict__ l2s, int n) {
  int i = blockIdx.x * blockDim.x + threadIdx.x;
  if (i < n) l2s[i] = __log2f(sz[i]);
}

// ---------------- GEMM: C[M,N] = A[M,K] @ B[N,K]^T + bias ----------------
struct GemmArgs { const ushortT* B; const float* bias; void* dst; int mode; };
// mode 0: Q -> bf16 [h][t][64] * 0.125   mode 1: K -> bf16 [h][t][64]
// mode 2: V -> bf16 [h][64][t] (transposed)      mode 3: fp32 [m][1024]

__global__ __launch_bounds__(256, 3) void gemm_bt_k(
    const ushortT* __restrict__ A, GemmArgs g0, GemmArgs g1, GemmArgs g2)
{
  constexpr int K = 1024;
  __shared__ __align__(16) ushortT As[128 * 64];
  __shared__ __align__(16) ushortT Bs[128 * 64];

  GemmArgs g = (blockIdx.y == 0) ? g0 : ((blockIdx.y == 1) ? g1 : g2);
  const ushortT* __restrict__ Bw = g.B;

  const int tid = threadIdx.x;
  const int wv = tid >> 6, ln = tid & 63;
  // XCD-locality decode (T1): nb = id&7 so each XCD serves ONE 128-col B-panel
  const int nb = blockIdx.x & 7, mb = blockIdx.x >> 3;      // 8 x 32 blocks
  const int m0 = mb * 128, n0 = nb * 128;
  const int wr = wv >> 1, wc = wv & 1;
  const int lrow = ln & 15, lq = ln >> 4;

  const int rstg = wv * 8 + (ln >> 3);
  const int ustg = (ln & 7) ^ (ln >> 3);

  f32x4 acc[4][4] = {};

  for (int kt = 0; kt < K; kt += 64) {
#pragma unroll
    for (int i = 0; i < 4; ++i) {
      int r = i * 32 + rstg;
      GLOAD_LDS16(A  + (size_t)(m0 + r) * K + kt + (ustg << 3), As + i * 2048 + wv * 512);
      GLOAD_LDS16(Bw + (size_t)(n0 + r) * K + kt + (ustg << 3), Bs + i * 2048 + wv * 512);
    }
    __syncthreads();
#pragma unroll
    for (int ks = 0; ks < 2; ++ks) {
      short8 a[4], b[4];
#pragma unroll
      for (int mi = 0; mi < 4; ++mi) {
        int ra = wr * 64 + mi * 16 + lrow;
        int u = (ks * 4 + lq) ^ (ra & 7);
        a[mi] = *(const short8*)(As + ra * 64 + (u << 3));
      }
#pragma unroll
      for (int ni = 0; ni < 4; ++ni) {
        int rb = wc * 64 + ni * 16 + lrow;
        int u = (ks * 4 + lq) ^ (rb & 7);
        b[ni] = *(const short8*)(Bs + rb * 64 + (u << 3));
      }
#pragma unroll
      for (int mi = 0; mi < 4; ++mi)
#pragma unroll
        for (int ni = 0; ni < 4; ++ni)
          acc[mi][ni] = __builtin_amdgcn_mfma_f32_16x16x32_bf16(a[mi], b[ni], acc[mi][ni], 0, 0, 0);
    }
    __syncthreads();
  }

  const int mode = g.mode;
  if (mode <= 1) {
    ushortT* dst = (ushortT*)g.dst;
    const float sc = (mode == 0) ? 0.125f : 1.0f;
#pragma unroll
    for (int ni = 0; ni < 4; ++ni) {
      int n = n0 + wc * 64 + ni * 16 + lrow;
      float bsv = g.bias[n];
      size_t base = ((size_t)(n >> 6) * L_SEQ) * HD + (n & 63);
#pragma unroll
      for (int mi = 0; mi < 4; ++mi)
#pragma unroll
        for (int r = 0; r < 4; ++r) {
          int m = m0 + wr * 64 + mi * 16 + lq * 4 + r;
          dst[base + (size_t)m * HD] = f2bf((acc[mi][ni][r] + bsv) * sc);
        }
    }
  } else if (mode == 2) {
    ushortT* dst = (ushortT*)g.dst;
#pragma unroll
    for (int ni = 0; ni < 4; ++ni) {
      int n = n0 + wc * 64 + ni * 16 + lrow;     // n == h*64+hd
      float bsv = g.bias[n];
      size_t base = (size_t)n * L_SEQ;
#pragma unroll
      for (int mi = 0; mi < 4; ++mi)
#pragma unroll
        for (int r = 0; r < 4; ++r) {
          int m = m0 + wr * 64 + mi * 16 + lq * 4 + r;
          dst[base + m] = f2bf(acc[mi][ni][r] + bsv);
        }
    }
  } else {
    float* dst = (float*)g.dst;
#pragma unroll
    for (int ni = 0; ni < 4; ++ni) {
      int n = n0 + wc * 64 + ni * 16 + lrow;
      float bsv = g.bias[n];
#pragma unroll
      for (int mi = 0; mi < 4; ++mi)
#pragma unroll
        for (int r = 0; r < 4; ++r) {
          int m = m0 + wr * 64 + mi * 16 + lq * 4 + r;
          dst[(size_t)m * EMBED + n] = acc[mi][ni][r] + bsv;
        }
    }
  }
}

// ---------------- flash attention (swapped 16x16, 32 q-rows per wave) --------
// R16 structure + R17: each wave owns 32 q-rows (two Q B-fragments, q-halves
// lrow and 16+lrow). Every K-fragment and V-fragment LDS read now feeds TWO
// MFMAs -> LDS bytes per q HALVE (the R16 bottleneck: ~109us of LDS-pipe busy
// in a 152us wall). Block = 128 q x 4 waves, grid 512 (2 blocks/CU; TLP drops
// but per-wave ILP doubles: two independent q-half chains). Same mappings,
// same kappa, bitwise-identical per-q-row math.
__global__ __launch_bounds__(256, 2) void attn_k(
    const ushortT* __restrict__ Q,   // [16][4096][64], pre-scaled by 0.125
    const ushortT* __restrict__ Kb,  // [16][4096][64]
    const ushortT* __restrict__ Vt,  // [16][64][4096]
    const float*   __restrict__ l2s, // [4096] log2(size)
    ushortT* __restrict__ O)         // [4096][1024] bf16
{
  __shared__ __align__(16) ushortT Ks[2][64 * 64];
  __shared__ __align__(16) ushortT Vs[2][64 * 64];

  const int id = blockIdx.x;                 // 0..511
  const int xcd = id & 7, s = id >> 3;       // s: 0..63
  const int h  = xcd * 2 + (s >> 5);         // head (2 per XCD)
  const int q0 = (s & 31) * 128;             // q-tile base (128 rows/block)

  const int tid = threadIdx.x;
  const int wv = tid >> 6, ln = tid & 63;
  const int lrow = ln & 15, lq = ln >> 4;

  // Q fragments for two q-halves: half hf covers q = q0 + wv*32 + hf*16 + lrow
  short8 qf[2][2];                 // [half][ks]
#pragma unroll
  for (int hf = 0; hf < 2; ++hf) {
    const ushortT* qp = Q + ((size_t)h * L_SEQ + q0 + wv * 32 + hf * 16 + lrow) * HD + lq * 8;
    qf[hf][0] = *(const short8*)qp;
    qf[hf][1] = *(const short8*)(qp + 32);
  }

  f32x4 o0[4] = {}, o1[4] = {};     // O^T per half: o[df][r] = O[16df+4lq+r][q]
  float mrun0 = -1e30f, lrun0 = 0.f;
  float mrun1 = -1e30f, lrun1 = 0.f;

  const int rstg = wv * 8 + (ln >> 3);
  const int ustg = (ln & 7) ^ (ln >> 3);

  const ushortT* kbase = Kb + ((size_t)h * L_SEQ + rstg) * HD + (ustg << 3);
  const ushortT* vbase = Vt + ((size_t)(h * HD) + rstg) * L_SEQ + (ustg << 3);

  auto STAGE = [&](int buf, int t0) {
#pragma unroll
    for (int i = 0; i < 2; ++i) {
      GLOAD_LDS16(kbase + t0 * 64 + i * (32 * HD),    &Ks[buf][i * 2048 + wv * 512]);
      GLOAD_LDS16(vbase + t0 + i * (32 * L_SEQ),      &Vs[buf][i * 2048 + wv * 512]);
    }
  };

  // loop-invariant V-read byte offsets (key groups {4lq,16+4lq,32+4lq,48+4lq},
  // slot = natural ^ (lrow&7); d = 16df+lrow so d&7 == lrow&7, df-invariant)
  const int sw = lrow & 7;
  const int vo0 = lrow * 128 + ((((lq >> 1))     ^ sw) << 4) + (lq & 1) * 8;
  const int vo1 = lrow * 128 + ((((lq >> 1) + 2) ^ sw) << 4) + (lq & 1) * 8;
  const int vo2 = lrow * 128 + ((((lq >> 1) + 4) ^ sw) << 4) + (lq & 1) * 8;
  const int vo3 = lrow * 128 + ((((lq >> 1) + 6) ^ sw) << 4) + (lq & 1) * 8;

  STAGE(0, 0);
  __syncthreads();                   // tile 0 resident

  constexpr int NT = L_SEQ / 64;
#pragma unroll 1
  for (int t = 0; t < NT; ++t) {
    const int cur = t & 1;
    if (t + 1 < NT) STAGE(cur ^ 1, (t + 1) * 64);   // overlaps entire compute
    const int t0 = t * 64;
    const ushortT* Kt = &Ks[cur][0];
    const char*    Vb = (const char*)&Vs[cur][0];

    // S^T = K Q for both q-halves; each K-fragment read feeds 2 MFMAs
    f32x4 s0[4] = {}, s1[4] = {};
    __builtin_amdgcn_s_setprio(1);
#pragma unroll
    for (int ks = 0; ks < 2; ++ks) {
#pragma unroll
      for (int f = 0; f < 4; ++f) {
        int key = f * 16 + lrow;
        int u = (ks * 4 + lq) ^ (key & 7);
        short8 kb = *(const short8*)(Kt + key * 64 + (u << 3));
        s0[f] = __builtin_amdgcn_mfma_f32_16x16x32_bf16(kb, qf[0][ks], s0[f], 0, 0, 0);
        s1[f] = __builtin_amdgcn_mfma_f32_16x16x32_bf16(kb, qf[1][ks], s1[f], 0, 0, 0);
      }
    }
    __builtin_amdgcn_s_setprio(0);

    // base-2 logits + log2(size_key); key of s[f][r] = 16f + 4lq + r
#pragma unroll
    for (int f = 0; f < 4; ++f) {
      f32x4 b = *(const f32x4*)(l2s + t0 + f * 16 + lq * 4);
#pragma unroll
      for (int r = 0; r < 4; ++r) {
        s0[f][r] = s0[f][r] * LOG2E + b[r];
        s1[f][r] = s1[f][r] * LOG2E + b[r];
      }
    }

    // softmax per half (lane owns both q rows): in-lane tree + 2 shfl steps
    float pm0 = fmaxf(fmaxf(fmaxf(s0[0][0], s0[0][1]), fmaxf(s0[0][2], s0[0][3])),
                      fmaxf(fmaxf(s0[1][0], s0[1][1]), fmaxf(s0[1][2], s0[1][3])));
    pm0 = fmaxf(pm0, fmaxf(fmaxf(fmaxf(s0[2][0], s0[2][1]), fmaxf(s0[2][2], s0[2][3])),
                           fmaxf(fmaxf(s0[3][0], s0[3][1]), fmaxf(s0[3][2], s0[3][3]))));
    float pm1 = fmaxf(fmaxf(fmaxf(s1[0][0], s1[0][1]), fmaxf(s1[0][2], s1[0][3])),
                      fmaxf(fmaxf(s1[1][0], s1[1][1]), fmaxf(s1[1][2], s1[1][3])));
    pm1 = fmaxf(pm1, fmaxf(fmaxf(fmaxf(s1[2][0], s1[2][1]), fmaxf(s1[2][2], s1[2][3])),
                           fmaxf(fmaxf(s1[3][0], s1[3][1]), fmaxf(s1[3][2], s1[3][3]))));
    pm0 = fmaxf(pm0, __shfl_xor(pm0, 16));
    pm0 = fmaxf(pm0, __shfl_xor(pm0, 32));
    pm1 = fmaxf(pm1, __shfl_xor(pm1, 16));
    pm1 = fmaxf(pm1, __shfl_xor(pm1, 32));
    float mnew0  = fmaxf(mrun0, pm0);
    float mnew1  = fmaxf(mrun1, pm1);
    float alpha0 = __builtin_amdgcn_exp2f(mrun0 - mnew0);
    float alpha1 = __builtin_amdgcn_exp2f(mrun1 - mnew1);
    mrun0 = mnew0; mrun1 = mnew1;

    float rs0 = 0.f, rs1 = 0.f;
#pragma unroll
    for (int f = 0; f < 4; ++f)
#pragma unroll
      for (int r = 0; r < 4; ++r) {
        float pv0 = __builtin_amdgcn_exp2f(s0[f][r] - mrun0);
        float pv1 = __builtin_amdgcn_exp2f(s1[f][r] - mrun1);
        s0[f][r] = pv0; rs0 += pv0;
        s1[f][r] = pv1; rs1 += pv1;
      }
    rs0 += __shfl_xor(rs0, 16);
    rs0 += __shfl_xor(rs0, 32);
    rs1 += __shfl_xor(rs1, 16);
    rs1 += __shfl_xor(rs1, 32);
    lrun0 = lrun0 * alpha0 + rs0;
    lrun1 = lrun1 * alpha1 + rs1;

    if (!__all(alpha0 == 1.0f && alpha1 == 1.0f)) {
#pragma unroll
      for (int df = 0; df < 4; ++df)
#pragma unroll
        for (int r = 0; r < 4; ++r) {
          o0[df][r] *= alpha0;
          o1[df][r] *= alpha1;
        }
    }

    // P -> bf16 B-fragments in-register (kappa ordering), per half
    short8 pb00, pb10, pb01, pb11;   // pb<kgroup><half>
    {
      unsigned a0 = cvtpk(s0[0][0], s0[0][1]), a1 = cvtpk(s0[0][2], s0[0][3]);
      unsigned a2 = cvtpk(s0[1][0], s0[1][1]), a3 = cvtpk(s0[1][2], s0[1][3]);
      unsigned a4 = cvtpk(s0[2][0], s0[2][1]), a5 = cvtpk(s0[2][2], s0[2][3]);
      unsigned a6 = cvtpk(s0[3][0], s0[3][1]), a7 = cvtpk(s0[3][2], s0[3][3]);
      pb00 = __builtin_bit_cast(short8, (uint4v){a0, a1, a2, a3});  // keys 0..31
      pb10 = __builtin_bit_cast(short8, (uint4v){a4, a5, a6, a7});  // keys 32..63
      unsigned b0 = cvtpk(s1[0][0], s1[0][1]), b1 = cvtpk(s1[0][2], s1[0][3]);
      unsigned b2 = cvtpk(s1[1][0], s1[1][1]), b3 = cvtpk(s1[1][2], s1[1][3]);
      unsigned b4 = cvtpk(s1[2][0], s1[2][1]), b5 = cvtpk(s1[2][2], s1[2][3]);
      unsigned b6 = cvtpk(s1[3][0], s1[3][1]), b7 = cvtpk(s1[3][2], s1[3][3]);
      pb01 = __builtin_bit_cast(short8, (uint4v){b0, b1, b2, b3});
      pb11 = __builtin_bit_cast(short8, (uint4v){b4, b5, b6, b7});
    }

    // O^T += V P : each V-fragment read feeds 2 MFMAs (both q-halves)
    __builtin_amdgcn_s_setprio(1);
#pragma unroll
    for (int df = 0; df < 4; ++df) {
      const char* vr = Vb + df * 2048;
      uint2 a0 = *(const uint2*)(vr + vo0);
      uint2 a1 = *(const uint2*)(vr + vo1);
      short8 va = __builtin_bit_cast(short8, (uint4v){a0.x, a0.y, a1.x, a1.y});
      o0[df] = __builtin_amdgcn_mfma_f32_16x16x32_bf16(va, pb00, o0[df], 0, 0, 0);
      o1[df] = __builtin_amdgcn_mfma_f32_16x16x32_bf16(va, pb01, o1[df], 0, 0, 0);
      uint2 a2 = *(const uint2*)(vr + vo2);
      uint2 a3 = *(const uint2*)(vr + vo3);
      short8 vb2 = __builtin_bit_cast(short8, (uint4v){a2.x, a2.y, a3.x, a3.y});
      o0[df] = __builtin_amdgcn_mfma_f32_16x16x32_bf16(vb2, pb10, o0[df], 0, 0, 0);
      o1[df] = __builtin_amdgcn_mfma_f32_16x16x32_bf16(vb2, pb11, o1[df], 0, 0, 0);
    }
    __builtin_amdgcn_s_setprio(0);

    __syncthreads();                 // drains next-tile loads; frees cur buffer
  }

  // epilogue: O[q][h*64+d] = o^T / lrun; 4 packed 8B stores per half
  float inv0 = 1.0f / lrun0, inv1 = 1.0f / lrun1;
  ushortT* ob0 = O + (size_t)(q0 + wv * 32 + lrow) * EMBED + h * HD;
  ushortT* ob1 = O + (size_t)(q0 + wv * 32 + 16 + lrow) * EMBED + h * HD;
#pragma unroll
  for (int df = 0; df < 4; ++df) {
    uint2 w0, w1;
    w0.x = (unsigned)f2bf(o0[df][0] * inv0) | ((unsigned)f2bf(o0[df][1] * inv0) << 16);
    w0.y = (unsigned)f2bf(o0[df][2] * inv0) | ((unsigned)f2bf(o0[df][3] * inv0) << 16);
    w1.x = (unsigned)f2bf(o1[df][0] * inv1) | ((unsigned)f2bf(o1[df][1] * inv1) << 16);
    w1.y = (unsigned)f2bf(o1[df][2] * inv1) | ((unsigned)f2bf(o1[df][3] * inv1) << 16);
    *(uint2*)(ob0 + df * 16 + lq * 4) = w0;
    *(uint2*)(ob1 + df * 16 + lq * 4) = w1;
  }
}

// ---------------- metric = mean over heads of K ----------------
__global__ void metric_k(const ushortT* __restrict__ Kb, float* __restrict__ out) {
  int idx = blockIdx.x * blockDim.x + threadIdx.x;   // t*8 + c8
  int t = idx >> 3, c8 = idx & 7;
  float acc[8] = {};
#pragma unroll
  for (int h = 0; h < HEADS; ++h) {
    short8 v = *(const short8*)(Kb + ((size_t)h * L_SEQ + t) * HD + c8 * 8);
#pragma unroll
    for (int j = 0; j < 8; ++j) acc[j] += bf2f((ushortT)v[j]);
  }
  float* dst = out + (size_t)t * HD + c8 * 8;
#pragma unroll
  for (int j = 0; j < 8; ++j) dst[j] = acc[j] * (1.0f / 16.0f);
}

extern "C" void kernel_launch(void* const* d_in, const int* in_sizes, int n_in,
                              void* d_out, int out_size, void* d_ws, size_t ws_size,
                              hipStream_t stream) {
  const float* hs = (const float*)d_in[0];
  const float* sz = (const float*)d_in[1];
  const float* wq = (const float*)d_in[2];
  const float* bq = (const float*)d_in[3];
  const float* wk = (const float*)d_in[4];
  const float* bk = (const float*)d_in[5];
  const float* wv = (const float*)d_in[6];
  const float* bv = (const float*)d_in[7];
  const float* wo = (const float*)d_in[8];
  const float* bo = (const float*)d_in[9];

  char* ws = (char*)d_ws;
  ushortT* hs_b = (ushortT*)(ws);                 // [4096][1024] bf16
  ushortT* wq_b = (ushortT*)(ws + (8u << 20));    // 4 weights bf16 (contiguous)
  ushortT* wk_b = wq_b + (1u << 20);
  ushortT* wv_b = wq_b + (2u << 20);
  ushortT* wo_b = wq_b + (3u << 20);
  ushortT* q_b  = (ushortT*)(ws + (16u << 20));   // [16][4096][64]
  ushortT* k_b  = (ushortT*)(ws + (24u << 20));   // [16][4096][64]
  ushortT* vt_b = (ushortT*)(ws + (32u << 20));   // [16][64][4096]
  ushortT* at_b = (ushortT*)(ws + (40u << 20));   // [4096][1024]
  float*   l2s  = (float*)(ws + (48u << 20));     // [4096]

  float* outp    = (float*)d_out;
  float* metricp = outp + (size_t)L_SEQ * EMBED;

  cast_bf16_k<<<L_SEQ * EMBED / 8 / 256, 256, 0, stream>>>(hs, hs_b, L_SEQ * EMBED / 8);
  cast4_bf16_k<<<2048, 256, 0, stream>>>(wq, wk, wv, wo, wq_b);
  l2size_k<<<L_SEQ / 256, 256, 0, stream>>>(sz, l2s, L_SEQ);

  GemmArgs aq{wq_b, bq, (void*)q_b, 0};
  GemmArgs ak{wk_b, bk, (void*)k_b, 1};
  GemmArgs av{wv_b, bv, (void*)vt_b, 2};
  gemm_bt_k<<<dim3(256, 3), 256, 0, stream>>>(hs_b, aq, ak, av);   // fused QKV

  metric_k<<<L_SEQ * 8 / 256, 256, 0, stream>>>(k_b, metricp);

  attn_k<<<512, 256, 0, stream>>>(q_b, k_b, vt_b, l2s, at_b);

  GemmArgs ao{wo_b, bo, (void*)outp, 3};
  gemm_bt_k<<<dim3(256, 1), 256, 0, stream>>>(at_b, ao, ao, ao);   // O projection
}